// Round 1
// baseline (382.627 us; speedup 1.0000x reference)
//
#include <hip/hip_runtime.h>
#include <hip/hip_bf16.h>

// ---------------------------------------------------------------------------
// PPMI-GNN forward: 2-layer GCN
//   h1 = x @ W1; a1 = relu(seg_sum(norm * h1[row] -> col) + b1)
//   h2 = a1 @ W2; out = seg_sum(norm * h2[row] -> col) + b2
// Strategy: build CSR (by destination col) on device each call, then
// deterministic per-node gather-reduce (no float atomics).
// ---------------------------------------------------------------------------

// Detect whether edge_index was pushed as int32 or int64.
// int64 (values < 50000) => every odd 32-bit word is a zero high-word.
__global__ void k_detect(const int* __restrict__ ei, int twoE, int* __restrict__ flag) {
    if (blockIdx.x == 0 && threadIdx.x == 0) {
        int zeros = 0, n = 0;
        for (int i = 1; i < twoE && n < 64; i += 2, ++n) zeros += (ei[i] == 0);
        *flag = (zeros == n) ? 1 : 0;   // 1 => int64 layout
    }
}

__device__ __forceinline__ void load_edge(const int* __restrict__ ei, int E, int e,
                                          int is64, int& r, int& c) {
    if (is64) { r = ei[2 * e]; c = ei[2 * (E + e)]; }
    else      { r = ei[e];     c = ei[E + e]; }
}

__global__ void k_count(const int* __restrict__ ei, int E, int N,
                        const int* __restrict__ flag, int* __restrict__ counts) {
    int e = blockIdx.x * blockDim.x + threadIdx.x;
    if (e >= E) return;
    int is64 = *flag;
    int r, c; load_edge(ei, E, e, is64, r, c);
    if ((unsigned)c < (unsigned)N && (unsigned)r < (unsigned)N)
        atomicAdd(&counts[c], 1);
}

// single-block exclusive scan over counts[0..n) -> offs[0..n], cursor copy
__global__ void k_scan(const int* __restrict__ counts, int* __restrict__ offs,
                       int* __restrict__ cursor, int n) {
    __shared__ int part[1024];
    const int tid   = threadIdx.x;
    const int chunk = (n + 1023) / 1024;
    const int beg   = tid * chunk;
    const int end   = min(beg + chunk, n);
    int s = 0;
    for (int i = beg; i < end; ++i) s += counts[i];
    part[tid] = s;
    __syncthreads();
    for (int d = 1; d < 1024; d <<= 1) {
        int v = (tid >= d) ? part[tid - d] : 0;
        __syncthreads();
        part[tid] += v;
        __syncthreads();
    }
    int base = (tid == 0) ? 0 : part[tid - 1];
    for (int i = beg; i < end; ++i) {
        offs[i] = base; cursor[i] = base;
        base += counts[i];
    }
    if (tid == 1023) offs[n] = part[1023];
}

__global__ void k_scatter(const int* __restrict__ ei, const float* __restrict__ nrm,
                          int E, int N, const int* __restrict__ flag,
                          int* __restrict__ cursor,
                          int* __restrict__ rows_s, float* __restrict__ norm_s) {
    int e = blockIdx.x * blockDim.x + threadIdx.x;
    if (e >= E) return;
    int is64 = *flag;
    int r, c; load_edge(ei, E, e, is64, r, c);
    if ((unsigned)c < (unsigned)N && (unsigned)r < (unsigned)N) {
        int p = atomicAdd(&cursor[c], 1);
        rows_s[p] = r;
        norm_s[p] = nrm[e];
    }
}

// ---------------------------------------------------------------------------
// Simple f32 LDS-tiled GEMM: C[M,N] = A[M,K] @ B[K,N], BN == N (1-D grid on M)
// ---------------------------------------------------------------------------
template <int BM, int BN, int BK, int TM, int TN>
__global__ __launch_bounds__(256) void k_gemm(const float* __restrict__ A,
                                              const float* __restrict__ B,
                                              float* __restrict__ C,
                                              int M, int K, int N) {
    __shared__ float As[BK][BM + 1];   // +1 pad: kills 8-way bank conflict on store
    __shared__ float Bs[BK][BN];
    const int tid = threadIdx.x;
    const int m0  = blockIdx.x * BM;
    const int tx  = tid % (BN / TN);
    const int ty  = tid / (BN / TN);

    float acc[TM][TN] = {};

    for (int k0 = 0; k0 < K; k0 += BK) {
        // A tile: BM x BK, store transposed As[k][m]
        for (int i = tid; i < BM * BK / 4; i += 256) {
            int row = i / (BK / 4);
            int kq  = i % (BK / 4);
            float4 v = make_float4(0.f, 0.f, 0.f, 0.f);
            if (m0 + row < M)
                v = *(const float4*)(A + (size_t)(m0 + row) * K + k0 + kq * 4);
            As[kq * 4 + 0][row] = v.x;
            As[kq * 4 + 1][row] = v.y;
            As[kq * 4 + 2][row] = v.z;
            As[kq * 4 + 3][row] = v.w;
        }
        // B tile: BK x BN
        for (int i = tid; i < BK * BN / 4; i += 256) {
            int kk = (i * 4) / BN;
            int nn = (i * 4) % BN;
            *(float4*)&Bs[kk][nn] = *(const float4*)(B + (size_t)(k0 + kk) * N + nn);
        }
        __syncthreads();

        #pragma unroll
        for (int kk = 0; kk < BK; ++kk) {
            float a[TM], b[TN];
            #pragma unroll
            for (int i = 0; i < TM; ++i) a[i] = As[kk][ty * TM + i];
            #pragma unroll
            for (int j = 0; j < TN; ++j) b[j] = Bs[kk][tx * TN + j];
            #pragma unroll
            for (int i = 0; i < TM; ++i)
                #pragma unroll
                for (int j = 0; j < TN; ++j)
                    acc[i][j] = fmaf(a[i], b[j], acc[i][j]);
        }
        __syncthreads();
    }

    for (int i = 0; i < TM; ++i) {
        int m = m0 + ty * TM + i;
        if (m < M) {
            #pragma unroll
            for (int j = 0; j < TN; ++j)
                C[(size_t)m * N + tx * TN + j] = acc[i][j];
        }
    }
}

// ---------------------------------------------------------------------------
// Per-node gather-reduce: one wave per destination node.
//   out[n] = (relu?)( sum_e norm_s[e]*h[rows_s[e]] + bias )
// ---------------------------------------------------------------------------
template <int F, bool RELU>
__global__ __launch_bounds__(256) void k_agg(const float* __restrict__ h,
                                             const int* __restrict__ offs,
                                             const int* __restrict__ rows_s,
                                             const float* __restrict__ norm_s,
                                             const float* __restrict__ bias,
                                             float* __restrict__ out, int nnodes) {
    const int lane = threadIdx.x & 63;
    const int node = (blockIdx.x * blockDim.x + threadIdx.x) >> 6;
    if (node >= nnodes) return;
    const int beg = offs[node], end = offs[node + 1];

    if (F == 128) {
        float2 acc = make_float2(0.f, 0.f);
        for (int e = beg; e < end; ++e) {
            const float  w = norm_s[e];
            const float2 v = ((const float2*)(h + (size_t)rows_s[e] * F))[lane];
            acc.x = fmaf(w, v.x, acc.x);
            acc.y = fmaf(w, v.y, acc.y);
        }
        const float2 b = ((const float2*)bias)[lane];
        acc.x += b.x; acc.y += b.y;
        if (RELU) { acc.x = fmaxf(acc.x, 0.f); acc.y = fmaxf(acc.y, 0.f); }
        ((float2*)(out + (size_t)node * F))[lane] = acc;
    } else {  // F == 64
        float acc = 0.f;
        for (int e = beg; e < end; ++e)
            acc = fmaf(norm_s[e], h[(size_t)rows_s[e] * F + lane], acc);
        acc += bias[lane];
        if (RELU) acc = fmaxf(acc, 0.f);
        out[(size_t)node * F + lane] = acc;
    }
}

// ---------------------------------------------------------------------------

extern "C" void kernel_launch(void* const* d_in, const int* in_sizes, int n_in,
                              void* d_out, int out_size, void* d_ws, size_t ws_size,
                              hipStream_t stream) {
    const float* x   = (const float*)d_in[0];
    const int*   ei  = (const int*)d_in[1];
    const float* nrm = (const float*)d_in[2];
    const float* W1  = (const float*)d_in[3];
    const float* b1  = (const float*)d_in[4];
    const float* W2  = (const float*)d_in[5];
    const float* b2  = (const float*)d_in[6];
    float* out = (float*)d_out;

    const int HID  = in_sizes[4];            // 128
    const int FEAT = in_sizes[3] / HID;      // 256
    const int EMB  = in_sizes[5] / HID;      // 64
    const int Nn   = in_sizes[0] / FEAT;     // 50000
    const int E    = in_sizes[2];            // 550000

    char* p = (char*)d_ws;
    auto alloc = [&](size_t bytes) {
        char* r = p;
        p += (bytes + 255) & ~(size_t)255;
        return r;
    };
    float* h1     = (float*)alloc((size_t)Nn * HID * 4);
    float* a1     = (float*)alloc((size_t)Nn * HID * 4);
    float* h2     = (float*)alloc((size_t)Nn * EMB * 4);
    int*   counts = (int*)  alloc((size_t)Nn * 4);
    int*   offs   = (int*)  alloc((size_t)(Nn + 1) * 4);
    int*   cursor = (int*)  alloc((size_t)Nn * 4);
    int*   rows_s = (int*)  alloc((size_t)E * 4);
    float* norm_s = (float*)alloc((size_t)E * 4);
    int*   flag   = (int*)  alloc(256);

    // ---- CSR build (by destination) ----
    hipMemsetAsync(counts, 0, (size_t)Nn * 4, stream);
    k_detect<<<1, 64, 0, stream>>>(ei, 2 * E, flag);
    k_count<<<(E + 255) / 256, 256, 0, stream>>>(ei, E, Nn, flag, counts);
    k_scan<<<1, 1024, 0, stream>>>(counts, offs, cursor, Nn);
    k_scatter<<<(E + 255) / 256, 256, 0, stream>>>(ei, nrm, E, Nn, flag,
                                                   cursor, rows_s, norm_s);

    // ---- layer 1 ----
    k_gemm<64, 128, 32, 8, 4><<<(Nn + 63) / 64, 256, 0, stream>>>(x, W1, h1, Nn, FEAT, HID);
    k_agg<128, true><<<(Nn + 3) / 4, 256, 0, stream>>>(h1, offs, rows_s, norm_s, b1, a1, Nn);

    // ---- layer 2 ----
    k_gemm<64, 64, 32, 8, 2><<<(Nn + 63) / 64, 256, 0, stream>>>(a1, W2, h2, Nn, HID, EMB);
    k_agg<64, false><<<(Nn + 3) / 4, 256, 0, stream>>>(h2, offs, rows_s, norm_s, b2, out, Nn);
}

// Round 2
// 275.543 us; speedup vs baseline: 1.3886x; 1.3886x over previous
//
#include <hip/hip_runtime.h>
#include <hip/hip_bf16.h>

// ---------------------------------------------------------------------------
// PPMI-GNN forward: 2-layer GCN
//   h1 = x @ W1; a1 = relu(seg_sum(norm * h1[row] -> col) + b1)
//   h2 = a1 @ W2; out = seg_sum(norm * h2[row] -> col) + b2
// CSR (by destination col) built on device each call, then deterministic
// per-node gather-reduce (no float atomics).
// Round 2: parallel 3-phase scan (was 109us single-block), 1-wave detect.
// ---------------------------------------------------------------------------

// Detect whether edge_index was pushed as int32 or int64 (one wave).
// int64 (values < 2^31) => every odd 32-bit word is a zero high-word.
__global__ void k_detect(const int* __restrict__ ei, int twoE, int* __restrict__ flag) {
    const int lane = threadIdx.x;            // 64 threads
    const int i = 1 + 2 * lane;
    int z = (i < twoE) ? (ei[i] == 0) : 1;
    unsigned long long m = __ballot(z);
    if (lane == 0) *flag = (m == ~0ULL) ? 1 : 0;
}

__device__ __forceinline__ void load_edge(const int* __restrict__ ei, int E, int e,
                                          int is64, int& r, int& c) {
    if (is64) { r = ei[2 * e]; c = ei[2 * (E + e)]; }
    else      { r = ei[e];     c = ei[E + e]; }
}

__global__ void k_count(const int* __restrict__ ei, int E, int N,
                        const int* __restrict__ flag, int* __restrict__ counts) {
    int e = blockIdx.x * blockDim.x + threadIdx.x;
    if (e >= E) return;
    int is64 = *flag;
    int r, c; load_edge(ei, E, e, is64, r, c);
    if ((unsigned)c < (unsigned)N && (unsigned)r < (unsigned)N)
        atomicAdd(&counts[c], 1);
}

// ---------------- 3-phase multi-block exclusive scan ----------------------
// Phase A: per-block sums of 256*ITEMS-element chunks.
template <int ITEMS>
__global__ __launch_bounds__(256) void k_scan_partial(const int* __restrict__ counts,
                                                      int* __restrict__ partial, int n) {
    const int tid = threadIdx.x;
    const int base = blockIdx.x * 256 * ITEMS + tid * ITEMS;
    int s = 0;
    #pragma unroll
    for (int i = 0; i < ITEMS; ++i) {
        int idx = base + i;
        if (idx < n) s += counts[idx];
    }
    #pragma unroll
    for (int d = 32; d; d >>= 1) s += __shfl_down(s, d, 64);
    __shared__ int ws[4];
    if ((tid & 63) == 0) ws[tid >> 6] = s;
    __syncthreads();
    if (tid == 0) partial[blockIdx.x] = ws[0] + ws[1] + ws[2] + ws[3];
}

// Phase B: single-wave exclusive scan of block partials; writes offs[n]=total.
__global__ void k_scan_base(const int* __restrict__ partial, int* __restrict__ baseOf,
                            int* __restrict__ offs, int n, int nblocks) {
    const int lane = threadIdx.x;            // 64 threads
    int running = 0;
    for (int b0 = 0; b0 < nblocks; b0 += 64) {
        int idx = b0 + lane;
        int v = (idx < nblocks) ? partial[idx] : 0;
        int inc = v;
        #pragma unroll
        for (int d = 1; d < 64; d <<= 1) {
            int x = __shfl_up(inc, d, 64);
            if (lane >= d) inc += x;
        }
        if (idx < nblocks) baseOf[idx] = running + (inc - v);
        running += __shfl(inc, 63, 64);
    }
    if (lane == 0) offs[n] = running;
}

// Phase C: per-block rescan with base; writes offs + cursor.
template <int ITEMS>
__global__ __launch_bounds__(256) void k_scan_final(const int* __restrict__ counts,
                                                    const int* __restrict__ baseOf,
                                                    int* __restrict__ offs,
                                                    int* __restrict__ cursor, int n) {
    __shared__ int tsum[256];
    const int tid = threadIdx.x;
    const int base0 = blockIdx.x * 256 * ITEMS + tid * ITEMS;
    int v[ITEMS];
    int s = 0;
    #pragma unroll
    for (int i = 0; i < ITEMS; ++i) {
        int idx = base0 + i;
        v[i] = (idx < n) ? counts[idx] : 0;
        s += v[i];
    }
    tsum[tid] = s;
    __syncthreads();
    for (int d = 1; d < 256; d <<= 1) {
        int x = (tid >= d) ? tsum[tid - d] : 0;
        __syncthreads();
        tsum[tid] += x;
        __syncthreads();
    }
    int base = baseOf[blockIdx.x] + ((tid == 0) ? 0 : tsum[tid - 1]);
    #pragma unroll
    for (int i = 0; i < ITEMS; ++i) {
        int idx = base0 + i;
        if (idx < n) { offs[idx] = base; cursor[idx] = base; base += v[i]; }
    }
}

__global__ void k_scatter(const int* __restrict__ ei, const float* __restrict__ nrm,
                          int E, int N, const int* __restrict__ flag,
                          int* __restrict__ cursor,
                          int* __restrict__ rows_s, float* __restrict__ norm_s) {
    int e = blockIdx.x * blockDim.x + threadIdx.x;
    if (e >= E) return;
    int is64 = *flag;
    int r, c; load_edge(ei, E, e, is64, r, c);
    if ((unsigned)c < (unsigned)N && (unsigned)r < (unsigned)N) {
        int p = atomicAdd(&cursor[c], 1);
        rows_s[p] = r;
        norm_s[p] = nrm[e];
    }
}

// ---------------------------------------------------------------------------
// Simple f32 LDS-tiled GEMM: C[M,N] = A[M,K] @ B[K,N], BN == N (1-D grid on M)
// ---------------------------------------------------------------------------
template <int BM, int BN, int BK, int TM, int TN>
__global__ __launch_bounds__(256) void k_gemm(const float* __restrict__ A,
                                              const float* __restrict__ B,
                                              float* __restrict__ C,
                                              int M, int K, int N) {
    __shared__ float As[BK][BM + 1];
    __shared__ float Bs[BK][BN];
    const int tid = threadIdx.x;
    const int m0  = blockIdx.x * BM;
    const int tx  = tid % (BN / TN);
    const int ty  = tid / (BN / TN);

    float acc[TM][TN] = {};

    for (int k0 = 0; k0 < K; k0 += BK) {
        for (int i = tid; i < BM * BK / 4; i += 256) {
            int row = i / (BK / 4);
            int kq  = i % (BK / 4);
            float4 v = make_float4(0.f, 0.f, 0.f, 0.f);
            if (m0 + row < M)
                v = *(const float4*)(A + (size_t)(m0 + row) * K + k0 + kq * 4);
            As[kq * 4 + 0][row] = v.x;
            As[kq * 4 + 1][row] = v.y;
            As[kq * 4 + 2][row] = v.z;
            As[kq * 4 + 3][row] = v.w;
        }
        for (int i = tid; i < BK * BN / 4; i += 256) {
            int kk = (i * 4) / BN;
            int nn = (i * 4) % BN;
            *(float4*)&Bs[kk][nn] = *(const float4*)(B + (size_t)(k0 + kk) * N + nn);
        }
        __syncthreads();

        #pragma unroll
        for (int kk = 0; kk < BK; ++kk) {
            float a[TM], b[TN];
            #pragma unroll
            for (int i = 0; i < TM; ++i) a[i] = As[kk][ty * TM + i];
            #pragma unroll
            for (int j = 0; j < TN; ++j) b[j] = Bs[kk][tx * TN + j];
            #pragma unroll
            for (int i = 0; i < TM; ++i)
                #pragma unroll
                for (int j = 0; j < TN; ++j)
                    acc[i][j] = fmaf(a[i], b[j], acc[i][j]);
        }
        __syncthreads();
    }

    for (int i = 0; i < TM; ++i) {
        int m = m0 + ty * TM + i;
        if (m < M) {
            #pragma unroll
            for (int j = 0; j < TN; ++j)
                C[(size_t)m * N + tx * TN + j] = acc[i][j];
        }
    }
}

// ---------------------------------------------------------------------------
// Per-node gather-reduce: one wave per destination node.
// ---------------------------------------------------------------------------
template <int F, bool RELU>
__global__ __launch_bounds__(256) void k_agg(const float* __restrict__ h,
                                             const int* __restrict__ offs,
                                             const int* __restrict__ rows_s,
                                             const float* __restrict__ norm_s,
                                             const float* __restrict__ bias,
                                             float* __restrict__ out, int nnodes) {
    const int lane = threadIdx.x & 63;
    const int node = (blockIdx.x * blockDim.x + threadIdx.x) >> 6;
    if (node >= nnodes) return;
    const int beg = offs[node], end = offs[node + 1];

    if (F == 128) {
        float2 acc = make_float2(0.f, 0.f);
        for (int e = beg; e < end; ++e) {
            const float  w = norm_s[e];
            const float2 v = ((const float2*)(h + (size_t)rows_s[e] * F))[lane];
            acc.x = fmaf(w, v.x, acc.x);
            acc.y = fmaf(w, v.y, acc.y);
        }
        const float2 b = ((const float2*)bias)[lane];
        acc.x += b.x; acc.y += b.y;
        if (RELU) { acc.x = fmaxf(acc.x, 0.f); acc.y = fmaxf(acc.y, 0.f); }
        ((float2*)(out + (size_t)node * F))[lane] = acc;
    } else {  // F == 64
        float acc = 0.f;
        for (int e = beg; e < end; ++e)
            acc = fmaf(norm_s[e], h[(size_t)rows_s[e] * F + lane], acc);
        acc += bias[lane];
        if (RELU) acc = fmaxf(acc, 0.f);
        out[(size_t)node * F + lane] = acc;
    }
}

// ---------------------------------------------------------------------------

extern "C" void kernel_launch(void* const* d_in, const int* in_sizes, int n_in,
                              void* d_out, int out_size, void* d_ws, size_t ws_size,
                              hipStream_t stream) {
    const float* x   = (const float*)d_in[0];
    const int*   ei  = (const int*)d_in[1];
    const float* nrm = (const float*)d_in[2];
    const float* W1  = (const float*)d_in[3];
    const float* b1  = (const float*)d_in[4];
    const float* W2  = (const float*)d_in[5];
    const float* b2  = (const float*)d_in[6];
    float* out = (float*)d_out;

    const int HID  = in_sizes[4];            // 128
    const int FEAT = in_sizes[3] / HID;      // 256
    const int EMB  = in_sizes[5] / HID;      // 64
    const int Nn   = in_sizes[0] / FEAT;     // 50000
    const int E    = in_sizes[2];            // 550000

    char* p = (char*)d_ws;
    auto alloc = [&](size_t bytes) {
        char* r = p;
        p += (bytes + 255) & ~(size_t)255;
        return r;
    };
    float* h1      = (float*)alloc((size_t)Nn * HID * 4);
    float* a1      = (float*)alloc((size_t)Nn * HID * 4);
    float* h2      = (float*)alloc((size_t)Nn * EMB * 4);
    int*   counts  = (int*)  alloc((size_t)Nn * 4);
    int*   offs    = (int*)  alloc((size_t)(Nn + 1) * 4);
    int*   cursor  = (int*)  alloc((size_t)Nn * 4);
    int*   rows_s  = (int*)  alloc((size_t)E * 4);
    float* norm_s  = (float*)alloc((size_t)E * 4);
    int*   flag    = (int*)  alloc(256);
    int*   partial = (int*)  alloc(1024 * 4);
    int*   baseOf  = (int*)  alloc(1024 * 4);

    // ---- CSR build (by destination) ----
    constexpr int SCAN_ITEMS = 8;                       // 2048 elems / block
    const int scanBlocks = (Nn + 256 * SCAN_ITEMS - 1) / (256 * SCAN_ITEMS);

    hipMemsetAsync(counts, 0, (size_t)Nn * 4, stream);
    k_detect<<<1, 64, 0, stream>>>(ei, 2 * E, flag);
    k_count<<<(E + 255) / 256, 256, 0, stream>>>(ei, E, Nn, flag, counts);
    k_scan_partial<SCAN_ITEMS><<<scanBlocks, 256, 0, stream>>>(counts, partial, Nn);
    k_scan_base<<<1, 64, 0, stream>>>(partial, baseOf, offs, Nn, scanBlocks);
    k_scan_final<SCAN_ITEMS><<<scanBlocks, 256, 0, stream>>>(counts, baseOf, offs, cursor, Nn);
    k_scatter<<<(E + 255) / 256, 256, 0, stream>>>(ei, nrm, E, Nn, flag,
                                                   cursor, rows_s, norm_s);

    // ---- layer 1 ----
    k_gemm<64, 128, 32, 8, 4><<<(Nn + 63) / 64, 256, 0, stream>>>(x, W1, h1, Nn, FEAT, HID);
    k_agg<128, true><<<(Nn + 3) / 4, 256, 0, stream>>>(h1, offs, rows_s, norm_s, b1, a1, Nn);

    // ---- layer 2 ----
    k_gemm<64, 64, 32, 8, 2><<<(Nn + 63) / 64, 256, 0, stream>>>(a1, W2, h2, Nn, HID, EMB);
    k_agg<64, false><<<(Nn + 3) / 4, 256, 0, stream>>>(h2, offs, rows_s, norm_s, b2, out, Nn);
}

// Round 3
// 225.272 us; speedup vs baseline: 1.6985x; 1.2232x over previous
//
#include <hip/hip_runtime.h>
#include <stdint.h>

// ---------------------------------------------------------------------------
// PPMI-GNN forward: 2-layer GCN with bf16-MFMA GEMMs.
//   h1 = x @ W1; a1 = relu(agg(h1) + b1)   [a1 stored bf16]
//   h2 = a1 @ W2; out = agg(h2) + b2
// CSR (by destination) built on device each call; deterministic per-node
// gather-reduce (no float atomics).
// Round 3: MFMA GEMM (bf16 in / f32 acc), conversion fused into staging/agg.
// ---------------------------------------------------------------------------

typedef __attribute__((ext_vector_type(8))) short short8;   // 8 bf16
typedef __attribute__((ext_vector_type(4))) float f32x4;

__device__ __forceinline__ unsigned short f2bf(float f) {   // RNE f32->bf16
    unsigned u = __float_as_uint(f);
    return (unsigned short)((u + 0x7FFFu + ((u >> 16) & 1u)) >> 16);
}

// ---------------- edge-index layout detect (int32 vs int64) ----------------
__global__ void k_detect(const int* __restrict__ ei, int twoE, int* __restrict__ flag) {
    const int lane = threadIdx.x;            // 64 threads
    const int i = 1 + 2 * lane;
    int z = (i < twoE) ? (ei[i] == 0) : 1;
    unsigned long long m = __ballot(z);
    if (lane == 0) *flag = (m == ~0ULL) ? 1 : 0;
}

__device__ __forceinline__ void load_edge(const int* __restrict__ ei, int E, int e,
                                          int is64, int& r, int& c) {
    if (is64) { r = ei[2 * e]; c = ei[2 * (E + e)]; }
    else      { r = ei[e];     c = ei[E + e]; }
}

__global__ void k_count(const int* __restrict__ ei, int E, int N,
                        const int* __restrict__ flag, int* __restrict__ counts) {
    int e = blockIdx.x * blockDim.x + threadIdx.x;
    if (e >= E) return;
    int is64 = *flag;
    int r, c; load_edge(ei, E, e, is64, r, c);
    if ((unsigned)c < (unsigned)N && (unsigned)r < (unsigned)N)
        atomicAdd(&counts[c], 1);
}

// ---------------- 3-phase multi-block exclusive scan ----------------------
template <int ITEMS>
__global__ __launch_bounds__(256) void k_scan_partial(const int* __restrict__ counts,
                                                      int* __restrict__ partial, int n) {
    const int tid = threadIdx.x;
    const int base = blockIdx.x * 256 * ITEMS + tid * ITEMS;
    int s = 0;
    #pragma unroll
    for (int i = 0; i < ITEMS; ++i) {
        int idx = base + i;
        if (idx < n) s += counts[idx];
    }
    #pragma unroll
    for (int d = 32; d; d >>= 1) s += __shfl_down(s, d, 64);
    __shared__ int ws[4];
    if ((tid & 63) == 0) ws[tid >> 6] = s;
    __syncthreads();
    if (tid == 0) partial[blockIdx.x] = ws[0] + ws[1] + ws[2] + ws[3];
}

__global__ void k_scan_base(const int* __restrict__ partial, int* __restrict__ baseOf,
                            int* __restrict__ offs, int n, int nblocks) {
    const int lane = threadIdx.x;            // 64 threads
    int running = 0;
    for (int b0 = 0; b0 < nblocks; b0 += 64) {
        int idx = b0 + lane;
        int v = (idx < nblocks) ? partial[idx] : 0;
        int inc = v;
        #pragma unroll
        for (int d = 1; d < 64; d <<= 1) {
            int x = __shfl_up(inc, d, 64);
            if (lane >= d) inc += x;
        }
        if (idx < nblocks) baseOf[idx] = running + (inc - v);
        running += __shfl(inc, 63, 64);
    }
    if (lane == 0) offs[n] = running;
}

template <int ITEMS>
__global__ __launch_bounds__(256) void k_scan_final(const int* __restrict__ counts,
                                                    const int* __restrict__ baseOf,
                                                    int* __restrict__ offs,
                                                    int* __restrict__ cursor, int n) {
    __shared__ int tsum[256];
    const int tid = threadIdx.x;
    const int base0 = blockIdx.x * 256 * ITEMS + tid * ITEMS;
    int v[ITEMS];
    int s = 0;
    #pragma unroll
    for (int i = 0; i < ITEMS; ++i) {
        int idx = base0 + i;
        v[i] = (idx < n) ? counts[idx] : 0;
        s += v[i];
    }
    tsum[tid] = s;
    __syncthreads();
    for (int d = 1; d < 256; d <<= 1) {
        int x = (tid >= d) ? tsum[tid - d] : 0;
        __syncthreads();
        tsum[tid] += x;
        __syncthreads();
    }
    int base = baseOf[blockIdx.x] + ((tid == 0) ? 0 : tsum[tid - 1]);
    #pragma unroll
    for (int i = 0; i < ITEMS; ++i) {
        int idx = base0 + i;
        if (idx < n) { offs[idx] = base; cursor[idx] = base; base += v[i]; }
    }
}

__global__ void k_scatter(const int* __restrict__ ei, const float* __restrict__ nrm,
                          int E, int N, const int* __restrict__ flag,
                          int* __restrict__ cursor,
                          int* __restrict__ rows_s, float* __restrict__ norm_s) {
    int e = blockIdx.x * blockDim.x + threadIdx.x;
    if (e >= E) return;
    int is64 = *flag;
    int r, c; load_edge(ei, E, e, is64, r, c);
    if ((unsigned)c < (unsigned)N && (unsigned)r < (unsigned)N) {
        int p = atomicAdd(&cursor[c], 1);
        rows_s[p] = r;
        norm_s[p] = nrm[e];
    }
}

// ---------------- weight prep: W[K][N] f32 -> Wt[N][K] bf16 ----------------
__global__ void k_wprep(const float* __restrict__ W1, const float* __restrict__ W2,
                        unsigned short* __restrict__ W1t, unsigned short* __restrict__ W2t,
                        int FEAT, int HID, int EMB) {
    const int t1 = FEAT * HID, t2 = HID * EMB;
    for (int i = blockIdx.x * blockDim.x + threadIdx.x; i < t1 + t2;
         i += gridDim.x * blockDim.x) {
        if (i < t1) {
            int k = i / HID, n = i % HID;
            W1t[(size_t)n * FEAT + k] = f2bf(W1[i]);
        } else {
            int j = i - t1;
            int k = j / EMB, n = j % EMB;
            W2t[(size_t)n * HID + k] = f2bf(W2[j]);
        }
    }
}

// ---------------------------------------------------------------------------
// MFMA GEMM: C[M,N] f32 = A[M,K] @ Bt[N,K]^T, bf16 operands, BK=64.
// BM=64, 4 waves (2x2), wave tile (FM*16) x (FN*16); BN = 2*FN*16.
// LDS rows are 64 k-elems (128B), XOR-swizzled (byte ^= (row&7)<<4) on both
// write and read side (T2; reg-staged so both-sides swizzle is consistent).
// A_F32: A is f32 in global, converted to bf16 during staging.
// ---------------------------------------------------------------------------
template <int BM, int BN, int FM, int FN, bool A_F32>
__global__ __launch_bounds__(256) void k_gemm_mfma(const void* __restrict__ Ag,
                                                   const unsigned short* __restrict__ Bt,
                                                   float* __restrict__ C,
                                                   int M, int K, int N) {
    __shared__ char ldsA[BM * 128];
    __shared__ char ldsB[BN * 128];
    const int tid  = threadIdx.x;
    const int lane = tid & 63;
    const int wid  = tid >> 6;
    const int wr   = wid >> 1;
    const int wc   = wid & 1;
    const int m0   = blockIdx.x * BM;

    f32x4 acc[FM][FN] = {};

    for (int k0 = 0; k0 < K; k0 += 64) {
        // ---- stage A: BM x 64 -> bf16 LDS ----
        {
            const int row  = tid >> 2;        // BM==64
            const int kq   = tid & 3;         // 16 elems each
            const int grow = min(m0 + row, M - 1);
            const int kbb  = kq * 32;         // byte base within 128B row
            const int sw   = (row & 7) << 4;
            if (A_F32) {
                const float* src = (const float*)Ag + (size_t)grow * K + k0 + kq * 16;
                float4 v0 = ((const float4*)src)[0];
                float4 v1 = ((const float4*)src)[1];
                float4 v2 = ((const float4*)src)[2];
                float4 v3 = ((const float4*)src)[3];
                union { short8 s; unsigned short h[8]; } p0, p1;
                p0.h[0] = f2bf(v0.x); p0.h[1] = f2bf(v0.y);
                p0.h[2] = f2bf(v0.z); p0.h[3] = f2bf(v0.w);
                p0.h[4] = f2bf(v1.x); p0.h[5] = f2bf(v1.y);
                p0.h[6] = f2bf(v1.z); p0.h[7] = f2bf(v1.w);
                p1.h[0] = f2bf(v2.x); p1.h[1] = f2bf(v2.y);
                p1.h[2] = f2bf(v2.z); p1.h[3] = f2bf(v2.w);
                p1.h[4] = f2bf(v3.x); p1.h[5] = f2bf(v3.y);
                p1.h[6] = f2bf(v3.z); p1.h[7] = f2bf(v3.w);
                *(short8*)(ldsA + row * 128 + ( kbb       ^ sw)) = p0.s;
                *(short8*)(ldsA + row * 128 + ((kbb + 16) ^ sw)) = p1.s;
            } else {
                const unsigned short* src =
                    (const unsigned short*)Ag + (size_t)grow * K + k0 + kq * 16;
                short8 s0 = ((const short8*)src)[0];
                short8 s1 = ((const short8*)src)[1];
                *(short8*)(ldsA + row * 128 + ( kbb       ^ sw)) = s0;
                *(short8*)(ldsA + row * 128 + ((kbb + 16) ^ sw)) = s1;
            }
        }
        // ---- stage B: BN x 64 -> bf16 LDS ----
        if (BN == 128 || tid < 128) {
            const int row = tid >> 1;
            const int kh  = tid & 1;          // 32 elems each
            const int sw  = (row & 7) << 4;
            const short8* src = (const short8*)(Bt + (size_t)row * K + k0 + kh * 32);
            #pragma unroll
            for (int j = 0; j < 4; ++j) {
                short8 s = src[j];
                int kb = kh * 64 + j * 16;
                *(short8*)(ldsB + row * 128 + (kb ^ sw)) = s;
            }
        }
        __syncthreads();

        #pragma unroll
        for (int s = 0; s < 2; ++s) {
            const int klo = s * 64 + (lane >> 4) * 16;
            short8 af[FM], bfv[FN];
            #pragma unroll
            for (int i = 0; i < FM; ++i) {
                int r = wr * (FM * 16) + i * 16 + (lane & 15);
                af[i] = *(const short8*)(ldsA + r * 128 + (klo ^ ((r & 7) << 4)));
            }
            #pragma unroll
            for (int j = 0; j < FN; ++j) {
                int n = wc * (FN * 16) + j * 16 + (lane & 15);
                bfv[j] = *(const short8*)(ldsB + n * 128 + (klo ^ ((n & 7) << 4)));
            }
            #pragma unroll
            for (int i = 0; i < FM; ++i)
                #pragma unroll
                for (int j = 0; j < FN; ++j)
                    acc[i][j] = __builtin_amdgcn_mfma_f32_16x16x32_bf16(
                        af[i], bfv[j], acc[i][j], 0, 0, 0);
        }
        __syncthreads();
    }

    // epilogue: C/D layout col=lane&15, row=(lane>>4)*4+reg (m89/m91)
    #pragma unroll
    for (int i = 0; i < FM; ++i) {
        const int rbase = m0 + wr * (FM * 16) + i * 16 + ((lane >> 4) << 2);
        #pragma unroll
        for (int j = 0; j < FN; ++j) {
            const int c = wc * (FN * 16) + j * 16 + (lane & 15);
            #pragma unroll
            for (int r = 0; r < 4; ++r)
                if (rbase + r < M) C[(size_t)(rbase + r) * N + c] = acc[i][j][r];
        }
    }
}

// ---------------------------------------------------------------------------
// Per-node gather-reduce: one wave per destination node.
// OUT_BF16: write result as packed bf16 (feeds next MFMA GEMM directly).
// ---------------------------------------------------------------------------
template <int F, bool RELU, bool OUT_BF16>
__global__ __launch_bounds__(256) void k_agg(const float* __restrict__ h,
                                             const int* __restrict__ offs,
                                             const int* __restrict__ rows_s,
                                             const float* __restrict__ norm_s,
                                             const float* __restrict__ bias,
                                             void* __restrict__ outp, int nnodes) {
    const int lane = threadIdx.x & 63;
    const int node = (blockIdx.x * blockDim.x + threadIdx.x) >> 6;
    if (node >= nnodes) return;
    const int beg = offs[node], end = offs[node + 1];

    if (F == 128) {
        float2 acc = make_float2(0.f, 0.f);
        for (int e = beg; e < end; ++e) {
            const float  w = norm_s[e];
            const float2 v = ((const float2*)(h + (size_t)rows_s[e] * F))[lane];
            acc.x = fmaf(w, v.x, acc.x);
            acc.y = fmaf(w, v.y, acc.y);
        }
        const float2 b = ((const float2*)bias)[lane];
        acc.x += b.x; acc.y += b.y;
        if (RELU) { acc.x = fmaxf(acc.x, 0.f); acc.y = fmaxf(acc.y, 0.f); }
        if (OUT_BF16) {
            unsigned pack = (unsigned)f2bf(acc.x) | ((unsigned)f2bf(acc.y) << 16);
            ((unsigned*)outp)[(size_t)node * 64 + lane] = pack;
        } else {
            ((float2*)((float*)outp + (size_t)node * F))[lane] = acc;
        }
    } else {  // F == 64, f32 out
        float acc = 0.f;
        for (int e = beg; e < end; ++e)
            acc = fmaf(norm_s[e], h[(size_t)rows_s[e] * F + lane], acc);
        acc += bias[lane];
        if (RELU) acc = fmaxf(acc, 0.f);
        ((float*)outp)[(size_t)node * F + lane] = acc;
    }
}

// ---------------------------------------------------------------------------

extern "C" void kernel_launch(void* const* d_in, const int* in_sizes, int n_in,
                              void* d_out, int out_size, void* d_ws, size_t ws_size,
                              hipStream_t stream) {
    const float* x   = (const float*)d_in[0];
    const int*   ei  = (const int*)d_in[1];
    const float* nrm = (const float*)d_in[2];
    const float* W1  = (const float*)d_in[3];
    const float* b1  = (const float*)d_in[4];
    const float* W2  = (const float*)d_in[5];
    const float* b2  = (const float*)d_in[6];
    float* out = (float*)d_out;

    const int HID  = in_sizes[4];            // 128
    const int FEAT = in_sizes[3] / HID;      // 256
    const int EMB  = in_sizes[5] / HID;      // 64
    const int Nn   = in_sizes[0] / FEAT;     // 50000
    const int E    = in_sizes[2];            // 550000

    char* p = (char*)d_ws;
    auto alloc = [&](size_t bytes) {
        char* r = p;
        p += (bytes + 255) & ~(size_t)255;
        return r;
    };
    float*          h1      = (float*)         alloc((size_t)Nn * HID * 4);
    unsigned short* a1b     = (unsigned short*)alloc((size_t)Nn * HID * 2);
    float*          h2      = (float*)         alloc((size_t)Nn * EMB * 4);
    unsigned short* W1t     = (unsigned short*)alloc((size_t)HID * FEAT * 2);
    unsigned short* W2t     = (unsigned short*)alloc((size_t)EMB * HID * 2);
    int*            counts  = (int*)           alloc((size_t)Nn * 4);
    int*            offs    = (int*)           alloc((size_t)(Nn + 1) * 4);
    int*            cursor  = (int*)           alloc((size_t)Nn * 4);
    int*            rows_s  = (int*)           alloc((size_t)E * 4);
    float*          norm_s  = (float*)         alloc((size_t)E * 4);
    int*            flag    = (int*)           alloc(256);
    int*            partial = (int*)           alloc(1024 * 4);
    int*            baseOf  = (int*)           alloc(1024 * 4);

    // ---- CSR build (by destination) ----
    constexpr int SCAN_ITEMS = 8;
    const int scanBlocks = (Nn + 256 * SCAN_ITEMS - 1) / (256 * SCAN_ITEMS);

    hipMemsetAsync(counts, 0, (size_t)Nn * 4, stream);
    k_detect<<<1, 64, 0, stream>>>(ei, 2 * E, flag);
    k_wprep<<<64, 256, 0, stream>>>(W1, W2, W1t, W2t, FEAT, HID, EMB);
    k_count<<<(E + 255) / 256, 256, 0, stream>>>(ei, E, Nn, flag, counts);
    k_scan_partial<SCAN_ITEMS><<<scanBlocks, 256, 0, stream>>>(counts, partial, Nn);
    k_scan_base<<<1, 64, 0, stream>>>(partial, baseOf, offs, Nn, scanBlocks);
    k_scan_final<SCAN_ITEMS><<<scanBlocks, 256, 0, stream>>>(counts, baseOf, offs, cursor, Nn);
    k_scatter<<<(E + 255) / 256, 256, 0, stream>>>(ei, nrm, E, Nn, flag,
                                                   cursor, rows_s, norm_s);

    const int gemmBlocks = (Nn + 63) / 64;

    // ---- layer 1: h1 = x @ W1 (bf16 MFMA), a1b = bf16(relu(agg + b1)) ----
    k_gemm_mfma<64, 128, 2, 4, true><<<gemmBlocks, 256, 0, stream>>>(
        (const void*)x, W1t, h1, Nn, FEAT, HID);
    k_agg<128, true, true><<<(Nn + 3) / 4, 256, 0, stream>>>(
        h1, offs, rows_s, norm_s, b1, (void*)a1b, Nn);

    // ---- layer 2: h2 = a1 @ W2 (bf16 MFMA), out = agg + b2 ----
    k_gemm_mfma<64, 64, 2, 2, false><<<gemmBlocks, 256, 0, stream>>>(
        (const void*)a1b, W2t, h2, Nn, HID, EMB);
    k_agg<64, false, false><<<(Nn + 3) / 4, 256, 0, stream>>>(
        h2, offs, rows_s, norm_s, b2, (void*)out, Nn);
}

// Round 4
// 152.497 us; speedup vs baseline: 2.5091x; 1.4772x over previous
//
#include <hip/hip_runtime.h>
#include <stdint.h>

// ---------------------------------------------------------------------------
// PPMI-GNN forward: 2-layer GCN with bf16-MFMA GEMMs and bf16 gathers.
//   h1b = bf16(x @ W1); a1b = bf16(relu(agg(h1b) + b1))
//   h2b = bf16(a1b @ W2); out = agg(h2b) + b2
// CSR (by destination) built on device each call; per-node ranges padded to
// a multiple of 4 edges (pad: w=0,row=0) so the gather loop is branch-free
// and 4-deep unrolled (4 gathers in flight). No float atomics anywhere.
// ---------------------------------------------------------------------------

typedef __attribute__((ext_vector_type(8))) short short8;   // 8 bf16
typedef __attribute__((ext_vector_type(4))) float f32x4;

__device__ __forceinline__ unsigned short f2bf(float f) {   // RNE f32->bf16
    unsigned u = __float_as_uint(f);
    return (unsigned short)((u + 0x7FFFu + ((u >> 16) & 1u)) >> 16);
}
__device__ __forceinline__ float bf_lo(unsigned v) { return __uint_as_float(v << 16); }
__device__ __forceinline__ float bf_hi(unsigned v) { return __uint_as_float(v & 0xFFFF0000u); }
__device__ __forceinline__ float bf1(unsigned short v) { return __uint_as_float((unsigned)v << 16); }

// ---------------- edge-index layout detect (int32 vs int64) ----------------
__global__ void k_detect(const int* __restrict__ ei, int twoE, int* __restrict__ flag) {
    const int lane = threadIdx.x;            // 64 threads
    const int i = 1 + 2 * lane;
    int z = (i < twoE) ? (ei[i] == 0) : 1;
    unsigned long long m = __ballot(z);
    if (lane == 0) *flag = (m == ~0ULL) ? 1 : 0;
}

__device__ __forceinline__ void load_edge(const int* __restrict__ ei, int E, int e,
                                          int is64, int& r, int& c) {
    if (is64) { r = ei[2 * e]; c = ei[2 * (E + e)]; }
    else      { r = ei[e];     c = ei[E + e]; }
}

__global__ void k_count(const int* __restrict__ ei, int E, int N,
                        const int* __restrict__ flag, int* __restrict__ counts) {
    int e = blockIdx.x * blockDim.x + threadIdx.x;
    if (e >= E) return;
    int is64 = *flag;
    int r, c; load_edge(ei, E, e, is64, r, c);
    if ((unsigned)c < (unsigned)N && (unsigned)r < (unsigned)N)
        atomicAdd(&counts[c], 1);
}

// ---------------- 3-phase multi-block exclusive scan (PADDED to 4) --------
template <int ITEMS>
__global__ __launch_bounds__(256) void k_scan_partial(const int* __restrict__ counts,
                                                      int* __restrict__ partial, int n) {
    const int tid = threadIdx.x;
    const int base = blockIdx.x * 256 * ITEMS + tid * ITEMS;
    int s = 0;
    #pragma unroll
    for (int i = 0; i < ITEMS; ++i) {
        int idx = base + i;
        if (idx < n) s += (counts[idx] + 3) & ~3;     // padded count
    }
    #pragma unroll
    for (int d = 32; d; d >>= 1) s += __shfl_down(s, d, 64);
    __shared__ int ws[4];
    if ((tid & 63) == 0) ws[tid >> 6] = s;
    __syncthreads();
    if (tid == 0) partial[blockIdx.x] = ws[0] + ws[1] + ws[2] + ws[3];
}

__global__ void k_scan_base(const int* __restrict__ partial, int* __restrict__ baseOf,
                            int* __restrict__ offs, int n, int nblocks) {
    const int lane = threadIdx.x;            // 64 threads
    int running = 0;
    for (int b0 = 0; b0 < nblocks; b0 += 64) {
        int idx = b0 + lane;
        int v = (idx < nblocks) ? partial[idx] : 0;
        int inc = v;
        #pragma unroll
        for (int d = 1; d < 64; d <<= 1) {
            int x = __shfl_up(inc, d, 64);
            if (lane >= d) inc += x;
        }
        if (idx < nblocks) baseOf[idx] = running + (inc - v);
        running += __shfl(inc, 63, 64);
    }
    if (lane == 0) offs[n] = running;
}

// Phase C: rescan with base; writes offs+cursor and zero-fills pad slots.
template <int ITEMS>
__global__ __launch_bounds__(256) void k_scan_final(const int* __restrict__ counts,
                                                    const int* __restrict__ baseOf,
                                                    int* __restrict__ offs,
                                                    int* __restrict__ cursor,
                                                    int* __restrict__ rows_s,
                                                    float* __restrict__ norm_s, int n) {
    __shared__ int tsum[256];
    const int tid = threadIdx.x;
    const int base0 = blockIdx.x * 256 * ITEMS + tid * ITEMS;
    int v[ITEMS];
    int s = 0;
    #pragma unroll
    for (int i = 0; i < ITEMS; ++i) {
        int idx = base0 + i;
        v[i] = (idx < n) ? counts[idx] : 0;
        s += (v[i] + 3) & ~3;
    }
    tsum[tid] = s;
    __syncthreads();
    for (int d = 1; d < 256; d <<= 1) {
        int x = (tid >= d) ? tsum[tid - d] : 0;
        __syncthreads();
        tsum[tid] += x;
        __syncthreads();
    }
    int base = baseOf[blockIdx.x] + ((tid == 0) ? 0 : tsum[tid - 1]);
    #pragma unroll
    for (int i = 0; i < ITEMS; ++i) {
        int idx = base0 + i;
        if (idx < n) {
            offs[idx] = base; cursor[idx] = base;
            int pad = (v[i] + 3) & ~3;
            for (int j = v[i]; j < pad; ++j) {     // <=3 pad slots
                rows_s[base + j] = 0;
                norm_s[base + j] = 0.0f;
            }
            base += pad;
        }
    }
}

__global__ void k_scatter(const int* __restrict__ ei, const float* __restrict__ nrm,
                          int E, int N, const int* __restrict__ flag,
                          int* __restrict__ cursor,
                          int* __restrict__ rows_s, float* __restrict__ norm_s) {
    int e = blockIdx.x * blockDim.x + threadIdx.x;
    if (e >= E) return;
    int is64 = *flag;
    int r, c; load_edge(ei, E, e, is64, r, c);
    if ((unsigned)c < (unsigned)N && (unsigned)r < (unsigned)N) {
        int p = atomicAdd(&cursor[c], 1);
        rows_s[p] = r;
        norm_s[p] = nrm[e];
    }
}

// ---------------- weight prep: W[K][N] f32 -> Wt[N][K] bf16 ----------------
__global__ void k_wprep(const float* __restrict__ W1, const float* __restrict__ W2,
                        unsigned short* __restrict__ W1t, unsigned short* __restrict__ W2t,
                        int FEAT, int HID, int EMB) {
    const int t1 = FEAT * HID, t2 = HID * EMB;
    for (int i = blockIdx.x * blockDim.x + threadIdx.x; i < t1 + t2;
         i += gridDim.x * blockDim.x) {
        if (i < t1) {
            int k = i / HID, n = i % HID;
            W1t[(size_t)n * FEAT + k] = f2bf(W1[i]);
        } else {
            int j = i - t1;
            int k = j / EMB, n = j % EMB;
            W2t[(size_t)n * HID + k] = f2bf(W2[j]);
        }
    }
}

// ---------------------------------------------------------------------------
// MFMA GEMM: C[M,N] = A[M,K] @ Bt[N,K]^T, bf16 operands, f32 acc, BK=64.
// BM=64, 4 waves (2x2). LDS rows 128B, XOR-swizzled both sides (T2).
// A_F32: A is f32 in global (converted during staging). OUT_BF16: C bf16.
// ---------------------------------------------------------------------------
template <int BM, int BN, int FM, int FN, bool A_F32, bool OUT_BF16>
__global__ __launch_bounds__(256) void k_gemm_mfma(const void* __restrict__ Ag,
                                                   const unsigned short* __restrict__ Bt,
                                                   void* __restrict__ Cv,
                                                   int M, int K, int N) {
    __shared__ char ldsA[BM * 128];
    __shared__ char ldsB[BN * 128];
    const int tid  = threadIdx.x;
    const int lane = tid & 63;
    const int wid  = tid >> 6;
    const int wr   = wid >> 1;
    const int wc   = wid & 1;
    const int m0   = blockIdx.x * BM;

    f32x4 acc[FM][FN] = {};

    for (int k0 = 0; k0 < K; k0 += 64) {
        // ---- stage A: BM x 64 -> bf16 LDS ----
        {
            const int row  = tid >> 2;        // BM==64
            const int kq   = tid & 3;         // 16 elems each
            const int grow = min(m0 + row, M - 1);
            const int kbb  = kq * 32;
            const int sw   = (row & 7) << 4;
            if (A_F32) {
                const float* src = (const float*)Ag + (size_t)grow * K + k0 + kq * 16;
                float4 v0 = ((const float4*)src)[0];
                float4 v1 = ((const float4*)src)[1];
                float4 v2 = ((const float4*)src)[2];
                float4 v3 = ((const float4*)src)[3];
                union { short8 s; unsigned short h[8]; } p0, p1;
                p0.h[0] = f2bf(v0.x); p0.h[1] = f2bf(v0.y);
                p0.h[2] = f2bf(v0.z); p0.h[3] = f2bf(v0.w);
                p0.h[4] = f2bf(v1.x); p0.h[5] = f2bf(v1.y);
                p0.h[6] = f2bf(v1.z); p0.h[7] = f2bf(v1.w);
                p1.h[0] = f2bf(v2.x); p1.h[1] = f2bf(v2.y);
                p1.h[2] = f2bf(v2.z); p1.h[3] = f2bf(v2.w);
                p1.h[4] = f2bf(v3.x); p1.h[5] = f2bf(v3.y);
                p1.h[6] = f2bf(v3.z); p1.h[7] = f2bf(v3.w);
                *(short8*)(ldsA + row * 128 + ( kbb       ^ sw)) = p0.s;
                *(short8*)(ldsA + row * 128 + ((kbb + 16) ^ sw)) = p1.s;
            } else {
                const unsigned short* src =
                    (const unsigned short*)Ag + (size_t)grow * K + k0 + kq * 16;
                short8 s0 = ((const short8*)src)[0];
                short8 s1 = ((const short8*)src)[1];
                *(short8*)(ldsA + row * 128 + ( kbb       ^ sw)) = s0;
                *(short8*)(ldsA + row * 128 + ((kbb + 16) ^ sw)) = s1;
            }
        }
        // ---- stage B: BN x 64 -> bf16 LDS ----
        if (BN == 128 || tid < 128) {
            const int row = tid >> 1;
            const int kh  = tid & 1;
            const int sw  = (row & 7) << 4;
            const short8* src = (const short8*)(Bt + (size_t)row * K + k0 + kh * 32);
            #pragma unroll
            for (int j = 0; j < 4; ++j) {
                short8 s = src[j];
                int kb = kh * 64 + j * 16;
                *(short8*)(ldsB + row * 128 + (kb ^ sw)) = s;
            }
        }
        __syncthreads();

        #pragma unroll
        for (int s = 0; s < 2; ++s) {
            const int klo = s * 64 + (lane >> 4) * 16;
            short8 af[FM], bfv[FN];
            #pragma unroll
            for (int i = 0; i < FM; ++i) {
                int r = wr * (FM * 16) + i * 16 + (lane & 15);
                af[i] = *(const short8*)(ldsA + r * 128 + (klo ^ ((r & 7) << 4)));
            }
            #pragma unroll
            for (int j = 0; j < FN; ++j) {
                int n = wc * (FN * 16) + j * 16 + (lane & 15);
                bfv[j] = *(const short8*)(ldsB + n * 128 + (klo ^ ((n & 7) << 4)));
            }
            #pragma unroll
            for (int i = 0; i < FM; ++i)
                #pragma unroll
                for (int j = 0; j < FN; ++j)
                    acc[i][j] = __builtin_amdgcn_mfma_f32_16x16x32_bf16(
                        af[i], bfv[j], acc[i][j], 0, 0, 0);
        }
        __syncthreads();
    }

    // epilogue: C/D layout col=lane&15, row=(lane>>4)*4+reg
    #pragma unroll
    for (int i = 0; i < FM; ++i) {
        const int rbase = m0 + wr * (FM * 16) + i * 16 + ((lane >> 4) << 2);
        #pragma unroll
        for (int j = 0; j < FN; ++j) {
            const int c = wc * (FN * 16) + j * 16 + (lane & 15);
            #pragma unroll
            for (int r = 0; r < 4; ++r)
                if (rbase + r < M) {
                    if (OUT_BF16)
                        ((unsigned short*)Cv)[(size_t)(rbase + r) * N + c] = f2bf(acc[i][j][r]);
                    else
                        ((float*)Cv)[(size_t)(rbase + r) * N + c] = acc[i][j][r];
                }
        }
    }
}

// ---------------------------------------------------------------------------
// Per-node gather-reduce over bf16 h, one wave per node, 4-edge unroll.
// Edge ranges are padded to x4 (pad: w=0,row=0) -> branch-free inner loop.
// ---------------------------------------------------------------------------
template <int F, bool RELU, bool OUT_BF16>
__global__ __launch_bounds__(256) void k_agg(const unsigned short* __restrict__ h,
                                             const int* __restrict__ offs,
                                             const int* __restrict__ rows_s,
                                             const float* __restrict__ norm_s,
                                             const float* __restrict__ bias,
                                             void* __restrict__ outp, int nnodes) {
    const int lane = threadIdx.x & 63;
    const int wid  = __builtin_amdgcn_readfirstlane(threadIdx.x >> 6);
    const int node = blockIdx.x * 4 + wid;
    if (node >= nnodes) return;
    const int beg = offs[node], end = offs[node + 1];   // end-beg % 4 == 0

    if (F == 128) {
        const unsigned* hp = (const unsigned*)h;        // 64 x (2 bf16) per row
        float2 a0 = {0.f, 0.f}, a1 = {0.f, 0.f}, a2 = {0.f, 0.f}, a3 = {0.f, 0.f};
        for (int e = beg; e < end; e += 4) {
            const int   r0 = rows_s[e+0], r1 = rows_s[e+1], r2 = rows_s[e+2], r3 = rows_s[e+3];
            const float w0 = norm_s[e+0], w1 = norm_s[e+1], w2 = norm_s[e+2], w3 = norm_s[e+3];
            const unsigned v0 = hp[(size_t)r0 * 64 + lane];
            const unsigned v1 = hp[(size_t)r1 * 64 + lane];
            const unsigned v2 = hp[(size_t)r2 * 64 + lane];
            const unsigned v3 = hp[(size_t)r3 * 64 + lane];
            a0.x = fmaf(w0, bf_lo(v0), a0.x); a0.y = fmaf(w0, bf_hi(v0), a0.y);
            a1.x = fmaf(w1, bf_lo(v1), a1.x); a1.y = fmaf(w1, bf_hi(v1), a1.y);
            a2.x = fmaf(w2, bf_lo(v2), a2.x); a2.y = fmaf(w2, bf_hi(v2), a2.y);
            a3.x = fmaf(w3, bf_lo(v3), a3.x); a3.y = fmaf(w3, bf_hi(v3), a3.y);
        }
        float2 acc;
        acc.x = (a0.x + a1.x) + (a2.x + a3.x);
        acc.y = (a0.y + a1.y) + (a2.y + a3.y);
        const float2 b = ((const float2*)bias)[lane];
        acc.x += b.x; acc.y += b.y;
        if (RELU) { acc.x = fmaxf(acc.x, 0.f); acc.y = fmaxf(acc.y, 0.f); }
        if (OUT_BF16) {
            unsigned pack = (unsigned)f2bf(acc.x) | ((unsigned)f2bf(acc.y) << 16);
            ((unsigned*)outp)[(size_t)node * 64 + lane] = pack;
        } else {
            ((float2*)outp)[(size_t)node * 64 + lane] = acc;
        }
    } else {  // F == 64: one ushort per lane
        float a0 = 0.f, a1 = 0.f, a2 = 0.f, a3 = 0.f;
        for (int e = beg; e < end; e += 4) {
            const int   r0 = rows_s[e+0], r1 = rows_s[e+1], r2 = rows_s[e+2], r3 = rows_s[e+3];
            const float w0 = norm_s[e+0], w1 = norm_s[e+1], w2 = norm_s[e+2], w3 = norm_s[e+3];
            const float f0 = bf1(h[(size_t)r0 * 64 + lane]);
            const float f1 = bf1(h[(size_t)r1 * 64 + lane]);
            const float f2 = bf1(h[(size_t)r2 * 64 + lane]);
            const float f3 = bf1(h[(size_t)r3 * 64 + lane]);
            a0 = fmaf(w0, f0, a0); a1 = fmaf(w1, f1, a1);
            a2 = fmaf(w2, f2, a2); a3 = fmaf(w3, f3, a3);
        }
        float acc = (a0 + a1) + (a2 + a3) + bias[lane];
        if (RELU) acc = fmaxf(acc, 0.f);
        ((float*)outp)[(size_t)node * 64 + lane] = acc;
    }
}

// ---------------------------------------------------------------------------

extern "C" void kernel_launch(void* const* d_in, const int* in_sizes, int n_in,
                              void* d_out, int out_size, void* d_ws, size_t ws_size,
                              hipStream_t stream) {
    const float* x   = (const float*)d_in[0];
    const int*   ei  = (const int*)d_in[1];
    const float* nrm = (const float*)d_in[2];
    const float* W1  = (const float*)d_in[3];
    const float* b1  = (const float*)d_in[4];
    const float* W2  = (const float*)d_in[5];
    const float* b2  = (const float*)d_in[6];
    float* out = (float*)d_out;

    const int HID  = in_sizes[4];            // 128
    const int FEAT = in_sizes[3] / HID;      // 256
    const int EMB  = in_sizes[5] / HID;      // 64
    const int Nn   = in_sizes[0] / FEAT;     // 50000
    const int E    = in_sizes[2];            // 550000
    const int Epad = E + 4 * Nn + 64;        // CSR with per-node x4 padding

    char* p = (char*)d_ws;
    auto alloc = [&](size_t bytes) {
        char* r = p;
        p += (bytes + 255) & ~(size_t)255;
        return r;
    };
    unsigned short* h1b    = (unsigned short*)alloc((size_t)Nn * HID * 2);
    unsigned short* a1b    = (unsigned short*)alloc((size_t)Nn * HID * 2);
    unsigned short* h2b    = (unsigned short*)alloc((size_t)Nn * EMB * 2);
    unsigned short* W1t    = (unsigned short*)alloc((size_t)HID * FEAT * 2);
    unsigned short* W2t    = (unsigned short*)alloc((size_t)EMB * HID * 2);
    int*            counts = (int*)           alloc((size_t)Nn * 4);
    int*            offs   = (int*)           alloc((size_t)(Nn + 1) * 4);
    int*            cursor = (int*)           alloc((size_t)Nn * 4);
    int*            rows_s = (int*)           alloc((size_t)Epad * 4);
    float*          norm_s = (float*)         alloc((size_t)Epad * 4);
    int*            flag   = (int*)           alloc(256);
    int*            partial= (int*)           alloc(1024 * 4);
    int*            baseOf = (int*)           alloc(1024 * 4);

    // ---- CSR build (by destination, padded x4) ----
    constexpr int SCAN_ITEMS = 8;
    const int scanBlocks = (Nn + 256 * SCAN_ITEMS - 1) / (256 * SCAN_ITEMS);

    hipMemsetAsync(counts, 0, (size_t)Nn * 4, stream);
    k_detect<<<1, 64, 0, stream>>>(ei, 2 * E, flag);
    k_wprep<<<64, 256, 0, stream>>>(W1, W2, W1t, W2t, FEAT, HID, EMB);
    k_count<<<(E + 255) / 256, 256, 0, stream>>>(ei, E, Nn, flag, counts);
    k_scan_partial<SCAN_ITEMS><<<scanBlocks, 256, 0, stream>>>(counts, partial, Nn);
    k_scan_base<<<1, 64, 0, stream>>>(partial, baseOf, offs, Nn, scanBlocks);
    k_scan_final<SCAN_ITEMS><<<scanBlocks, 256, 0, stream>>>(counts, baseOf, offs,
                                                             cursor, rows_s, norm_s, Nn);
    k_scatter<<<(E + 255) / 256, 256, 0, stream>>>(ei, nrm, E, Nn, flag,
                                                   cursor, rows_s, norm_s);

    const int gemmBlocks = (Nn + 63) / 64;

    // ---- layer 1 ----
    k_gemm_mfma<64, 128, 2, 4, true, true><<<gemmBlocks, 256, 0, stream>>>(
        (const void*)x, W1t, (void*)h1b, Nn, FEAT, HID);
    k_agg<128, true, true><<<(Nn + 3) / 4, 256, 0, stream>>>(
        h1b, offs, rows_s, norm_s, b1, (void*)a1b, Nn);

    // ---- layer 2 ----
    k_gemm_mfma<64, 64, 2, 2, false, true><<<gemmBlocks, 256, 0, stream>>>(
        (const void*)a1b, W2t, (void*)h2b, Nn, HID, EMB);
    k_agg<64, false, false><<<(Nn + 3) / 4, 256, 0, stream>>>(
        h2b, offs, rows_s, norm_s, b2, (void*)out, Nn);
}

// Round 5
// 141.830 us; speedup vs baseline: 2.6978x; 1.0752x over previous
//
#include <hip/hip_runtime.h>
#include <stdint.h>

// ---------------------------------------------------------------------------
// PPMI-GNN forward: 2-layer GCN with bf16-MFMA GEMMs and bf16 gathers.
//   h1b = bf16(x @ W1); a1b = bf16(relu(agg(h1b) + b1))
//   h2b = bf16(a1b @ W2); out = agg(h2b) + b2
// CSR (by destination) built on device each call. CSR entry is PACKED into
// one u32: (row << 16) | fp16(norm)  [N < 65536] -> one random 4B write per
// edge in scatter (was 2x into a 2x-bigger region; write-amp 55MB measured).
// Per-node ranges padded to x4 (pad entry = 0) -> branch-free 4-deep gather.
// ---------------------------------------------------------------------------

typedef __attribute__((ext_vector_type(8))) short short8;   // 8 bf16
typedef __attribute__((ext_vector_type(4))) float f32x4;

__device__ __forceinline__ unsigned short f2bf(float f) {   // RNE f32->bf16
    unsigned u = __float_as_uint(f);
    return (unsigned short)((u + 0x7FFFu + ((u >> 16) & 1u)) >> 16);
}
__device__ __forceinline__ float bf_lo(unsigned v) { return __uint_as_float(v << 16); }
__device__ __forceinline__ float bf_hi(unsigned v) { return __uint_as_float(v & 0xFFFF0000u); }
__device__ __forceinline__ float bf1(unsigned short v) { return __uint_as_float((unsigned)v << 16); }
__device__ __forceinline__ unsigned short f2h(float f) {
    _Float16 h = (_Float16)f;
    return __builtin_bit_cast(unsigned short, h);
}
__device__ __forceinline__ float h2f(unsigned u16) {
    _Float16 h = __builtin_bit_cast(_Float16, (unsigned short)(u16 & 0xFFFFu));
    return (float)h;
}

// ---------------- edge-index layout detect (int32 vs int64) ----------------
__global__ void k_detect(const int* __restrict__ ei, int twoE, int* __restrict__ flag) {
    const int lane = threadIdx.x;            // 64 threads
    const int i = 1 + 2 * lane;
    int z = (i < twoE) ? (ei[i] == 0) : 1;
    unsigned long long m = __ballot(z);
    if (lane == 0) *flag = (m == ~0ULL) ? 1 : 0;
}

__device__ __forceinline__ void load_edge(const int* __restrict__ ei, int E, int e,
                                          int is64, int& r, int& c) {
    if (is64) { r = ei[2 * e]; c = ei[2 * (E + e)]; }
    else      { r = ei[e];     c = ei[E + e]; }
}

__global__ void k_count(const int* __restrict__ ei, int E, int N,
                        const int* __restrict__ flag, int* __restrict__ counts) {
    int e = blockIdx.x * blockDim.x + threadIdx.x;
    if (e >= E) return;
    int is64 = *flag;
    int r, c; load_edge(ei, E, e, is64, r, c);
    if ((unsigned)c < (unsigned)N && (unsigned)r < (unsigned)N)
        atomicAdd(&counts[c], 1);
}

// ---------------- 3-phase multi-block exclusive scan (PADDED to 4) --------
template <int ITEMS>
__global__ __launch_bounds__(256) void k_scan_partial(const int* __restrict__ counts,
                                                      int* __restrict__ partial, int n) {
    const int tid = threadIdx.x;
    const int base = blockIdx.x * 256 * ITEMS + tid * ITEMS;
    int s = 0;
    #pragma unroll
    for (int i = 0; i < ITEMS; ++i) {
        int idx = base + i;
        if (idx < n) s += (counts[idx] + 3) & ~3;     // padded count
    }
    #pragma unroll
    for (int d = 32; d; d >>= 1) s += __shfl_down(s, d, 64);
    __shared__ int ws[4];
    if ((tid & 63) == 0) ws[tid >> 6] = s;
    __syncthreads();
    if (tid == 0) partial[blockIdx.x] = ws[0] + ws[1] + ws[2] + ws[3];
}

__global__ void k_scan_base(const int* __restrict__ partial, int* __restrict__ baseOf,
                            int* __restrict__ offs, int n, int nblocks) {
    const int lane = threadIdx.x;            // 64 threads
    int running = 0;
    for (int b0 = 0; b0 < nblocks; b0 += 64) {
        int idx = b0 + lane;
        int v = (idx < nblocks) ? partial[idx] : 0;
        int inc = v;
        #pragma unroll
        for (int d = 1; d < 64; d <<= 1) {
            int x = __shfl_up(inc, d, 64);
            if (lane >= d) inc += x;
        }
        if (idx < nblocks) baseOf[idx] = running + (inc - v);
        running += __shfl(inc, 63, 64);
    }
    if (lane == 0) offs[n] = running;
}

// Phase C: rescan with base; writes offs+cursor, zero-fills pad entries.
template <int ITEMS>
__global__ __launch_bounds__(256) void k_scan_final(const int* __restrict__ counts,
                                                    const int* __restrict__ baseOf,
                                                    int* __restrict__ offs,
                                                    int* __restrict__ cursor,
                                                    unsigned* __restrict__ ent, int n) {
    __shared__ int tsum[256];
    const int tid = threadIdx.x;
    const int base0 = blockIdx.x * 256 * ITEMS + tid * ITEMS;
    int v[ITEMS];
    int s = 0;
    #pragma unroll
    for (int i = 0; i < ITEMS; ++i) {
        int idx = base0 + i;
        v[i] = (idx < n) ? counts[idx] : 0;
        s += (v[i] + 3) & ~3;
    }
    tsum[tid] = s;
    __syncthreads();
    for (int d = 1; d < 256; d <<= 1) {
        int x = (tid >= d) ? tsum[tid - d] : 0;
        __syncthreads();
        tsum[tid] += x;
        __syncthreads();
    }
    int base = baseOf[blockIdx.x] + ((tid == 0) ? 0 : tsum[tid - 1]);
    #pragma unroll
    for (int i = 0; i < ITEMS; ++i) {
        int idx = base0 + i;
        if (idx < n) {
            offs[idx] = base; cursor[idx] = base;
            int pad = (v[i] + 3) & ~3;
            for (int j = v[i]; j < pad; ++j)       // <=3 pad slots
                ent[base + j] = 0u;                // row 0, w = +0.0h
            base += pad;
        }
    }
}

__global__ void k_scatter(const int* __restrict__ ei, const float* __restrict__ nrm,
                          int E, int N, const int* __restrict__ flag,
                          int* __restrict__ cursor, unsigned* __restrict__ ent) {
    int e = blockIdx.x * blockDim.x + threadIdx.x;
    if (e >= E) return;
    int is64 = *flag;
    int r, c; load_edge(ei, E, e, is64, r, c);
    if ((unsigned)c < (unsigned)N && (unsigned)r < (unsigned)N) {
        int p = atomicAdd(&cursor[c], 1);
        ent[p] = ((unsigned)r << 16) | (unsigned)f2h(nrm[e]);
    }
}

// ---------------- weight prep: W[K][N] f32 -> Wt[N][K] bf16 ----------------
__global__ void k_wprep(const float* __restrict__ W1, const float* __restrict__ W2,
                        unsigned short* __restrict__ W1t, unsigned short* __restrict__ W2t,
                        int FEAT, int HID, int EMB) {
    const int t1 = FEAT * HID, t2 = HID * EMB;
    for (int i = blockIdx.x * blockDim.x + threadIdx.x; i < t1 + t2;
         i += gridDim.x * blockDim.x) {
        if (i < t1) {
            int k = i / HID, n = i % HID;
            W1t[(size_t)n * FEAT + k] = f2bf(W1[i]);
        } else {
            int j = i - t1;
            int k = j / EMB, n = j % EMB;
            W2t[(size_t)n * HID + k] = f2bf(W2[j]);
        }
    }
}

// ---------------------------------------------------------------------------
// MFMA GEMM: C[M,N] = A[M,K] @ Bt[N,K]^T, bf16 operands, f32 acc, BK=64.
// BM=64, 4 waves (2x2). LDS rows 128B, XOR-swizzled both sides (T2).
// ---------------------------------------------------------------------------
template <int BM, int BN, int FM, int FN, bool A_F32, bool OUT_BF16>
__global__ __launch_bounds__(256) void k_gemm_mfma(const void* __restrict__ Ag,
                                                   const unsigned short* __restrict__ Bt,
                                                   void* __restrict__ Cv,
                                                   int M, int K, int N) {
    __shared__ char ldsA[BM * 128];
    __shared__ char ldsB[BN * 128];
    const int tid  = threadIdx.x;
    const int lane = tid & 63;
    const int wid  = tid >> 6;
    const int wr   = wid >> 1;
    const int wc   = wid & 1;
    const int m0   = blockIdx.x * BM;

    f32x4 acc[FM][FN] = {};

    for (int k0 = 0; k0 < K; k0 += 64) {
        // ---- stage A: BM x 64 -> bf16 LDS ----
        {
            const int row  = tid >> 2;        // BM==64
            const int kq   = tid & 3;         // 16 elems each
            const int grow = min(m0 + row, M - 1);
            const int kbb  = kq * 32;
            const int sw   = (row & 7) << 4;
            if (A_F32) {
                const float* src = (const float*)Ag + (size_t)grow * K + k0 + kq * 16;
                float4 v0 = ((const float4*)src)[0];
                float4 v1 = ((const float4*)src)[1];
                float4 v2 = ((const float4*)src)[2];
                float4 v3 = ((const float4*)src)[3];
                union { short8 s; unsigned short h[8]; } p0, p1;
                p0.h[0] = f2bf(v0.x); p0.h[1] = f2bf(v0.y);
                p0.h[2] = f2bf(v0.z); p0.h[3] = f2bf(v0.w);
                p0.h[4] = f2bf(v1.x); p0.h[5] = f2bf(v1.y);
                p0.h[6] = f2bf(v1.z); p0.h[7] = f2bf(v1.w);
                p1.h[0] = f2bf(v2.x); p1.h[1] = f2bf(v2.y);
                p1.h[2] = f2bf(v2.z); p1.h[3] = f2bf(v2.w);
                p1.h[4] = f2bf(v3.x); p1.h[5] = f2bf(v3.y);
                p1.h[6] = f2bf(v3.z); p1.h[7] = f2bf(v3.w);
                *(short8*)(ldsA + row * 128 + ( kbb       ^ sw)) = p0.s;
                *(short8*)(ldsA + row * 128 + ((kbb + 16) ^ sw)) = p1.s;
            } else {
                const unsigned short* src =
                    (const unsigned short*)Ag + (size_t)grow * K + k0 + kq * 16;
                short8 s0 = ((const short8*)src)[0];
                short8 s1 = ((const short8*)src)[1];
                *(short8*)(ldsA + row * 128 + ( kbb       ^ sw)) = s0;
                *(short8*)(ldsA + row * 128 + ((kbb + 16) ^ sw)) = s1;
            }
        }
        // ---- stage B: BN x 64 -> bf16 LDS ----
        if (BN == 128 || tid < 128) {
            const int row = tid >> 1;
            const int kh  = tid & 1;
            const int sw  = (row & 7) << 4;
            const short8* src = (const short8*)(Bt + (size_t)row * K + k0 + kh * 32);
            #pragma unroll
            for (int j = 0; j < 4; ++j) {
                short8 s = src[j];
                int kb = kh * 64 + j * 16;
                *(short8*)(ldsB + row * 128 + (kb ^ sw)) = s;
            }
        }
        __syncthreads();

        #pragma unroll
        for (int s = 0; s < 2; ++s) {
            const int klo = s * 64 + (lane >> 4) * 16;
            short8 af[FM], bfv[FN];
            #pragma unroll
            for (int i = 0; i < FM; ++i) {
                int r = wr * (FM * 16) + i * 16 + (lane & 15);
                af[i] = *(const short8*)(ldsA + r * 128 + (klo ^ ((r & 7) << 4)));
            }
            #pragma unroll
            for (int j = 0; j < FN; ++j) {
                int n = wc * (FN * 16) + j * 16 + (lane & 15);
                bfv[j] = *(const short8*)(ldsB + n * 128 + (klo ^ ((n & 7) << 4)));
            }
            #pragma unroll
            for (int i = 0; i < FM; ++i)
                #pragma unroll
                for (int j = 0; j < FN; ++j)
                    acc[i][j] = __builtin_amdgcn_mfma_f32_16x16x32_bf16(
                        af[i], bfv[j], acc[i][j], 0, 0, 0);
        }
        __syncthreads();
    }

    // epilogue: C/D layout col=lane&15, row=(lane>>4)*4+reg
    #pragma unroll
    for (int i = 0; i < FM; ++i) {
        const int rbase = m0 + wr * (FM * 16) + i * 16 + ((lane >> 4) << 2);
        #pragma unroll
        for (int j = 0; j < FN; ++j) {
            const int c = wc * (FN * 16) + j * 16 + (lane & 15);
            #pragma unroll
            for (int r = 0; r < 4; ++r)
                if (rbase + r < M) {
                    if (OUT_BF16)
                        ((unsigned short*)Cv)[(size_t)(rbase + r) * N + c] = f2bf(acc[i][j][r]);
                    else
                        ((float*)Cv)[(size_t)(rbase + r) * N + c] = acc[i][j][r];
                }
        }
    }
}

// ---------------------------------------------------------------------------
// Per-node gather-reduce over bf16 h, one wave per node, 4-edge unroll.
// Edge entries packed u32 = (row<<16)|fp16(w); ranges padded to x4 (entry 0).
// ---------------------------------------------------------------------------
template <int F, bool RELU, bool OUT_BF16>
__global__ __launch_bounds__(256) void k_agg(const unsigned short* __restrict__ h,
                                             const int* __restrict__ offs,
                                             const unsigned* __restrict__ ent,
                                             const float* __restrict__ bias,
                                             void* __restrict__ outp, int nnodes) {
    const int lane = threadIdx.x & 63;
    const int wid  = __builtin_amdgcn_readfirstlane(threadIdx.x >> 6);
    const int node = blockIdx.x * 4 + wid;
    if (node >= nnodes) return;
    const int beg = offs[node], end = offs[node + 1];   // (end-beg) % 4 == 0

    if (F == 128) {
        const unsigned* hp = (const unsigned*)h;        // 64 x (2 bf16) per row
        float2 a0 = {0.f, 0.f}, a1 = {0.f, 0.f}, a2 = {0.f, 0.f}, a3 = {0.f, 0.f};
        for (int e = beg; e < end; e += 4) {
            const unsigned e0 = ent[e+0], e1 = ent[e+1], e2 = ent[e+2], e3 = ent[e+3];
            const float w0 = h2f(e0), w1 = h2f(e1), w2 = h2f(e2), w3 = h2f(e3);
            const unsigned v0 = hp[(size_t)(e0 >> 16) * 64 + lane];
            const unsigned v1 = hp[(size_t)(e1 >> 16) * 64 + lane];
            const unsigned v2 = hp[(size_t)(e2 >> 16) * 64 + lane];
            const unsigned v3 = hp[(size_t)(e3 >> 16) * 64 + lane];
            a0.x = fmaf(w0, bf_lo(v0), a0.x); a0.y = fmaf(w0, bf_hi(v0), a0.y);
            a1.x = fmaf(w1, bf_lo(v1), a1.x); a1.y = fmaf(w1, bf_hi(v1), a1.y);
            a2.x = fmaf(w2, bf_lo(v2), a2.x); a2.y = fmaf(w2, bf_hi(v2), a2.y);
            a3.x = fmaf(w3, bf_lo(v3), a3.x); a3.y = fmaf(w3, bf_hi(v3), a3.y);
        }
        float2 acc;
        acc.x = (a0.x + a1.x) + (a2.x + a3.x);
        acc.y = (a0.y + a1.y) + (a2.y + a3.y);
        const float2 b = ((const float2*)bias)[lane];
        acc.x += b.x; acc.y += b.y;
        if (RELU) { acc.x = fmaxf(acc.x, 0.f); acc.y = fmaxf(acc.y, 0.f); }
        if (OUT_BF16) {
            unsigned pack = (unsigned)f2bf(acc.x) | ((unsigned)f2bf(acc.y) << 16);
            ((unsigned*)outp)[(size_t)node * 64 + lane] = pack;
        } else {
            ((float2*)outp)[(size_t)node * 64 + lane] = acc;
        }
    } else {  // F == 64: one ushort per lane
        float a0 = 0.f, a1 = 0.f, a2 = 0.f, a3 = 0.f;
        for (int e = beg; e < end; e += 4) {
            const unsigned e0 = ent[e+0], e1 = ent[e+1], e2 = ent[e+2], e3 = ent[e+3];
            const float w0 = h2f(e0), w1 = h2f(e1), w2 = h2f(e2), w3 = h2f(e3);
            const float f0 = bf1(h[(size_t)(e0 >> 16) * 64 + lane]);
            const float f1 = bf1(h[(size_t)(e1 >> 16) * 64 + lane]);
            const float f2 = bf1(h[(size_t)(e2 >> 16) * 64 + lane]);
            const float f3 = bf1(h[(size_t)(e3 >> 16) * 64 + lane]);
            a0 = fmaf(w0, f0, a0); a1 = fmaf(w1, f1, a1);
            a2 = fmaf(w2, f2, a2); a3 = fmaf(w3, f3, a3);
        }
        float acc = (a0 + a1) + (a2 + a3) + bias[lane];
        if (RELU) acc = fmaxf(acc, 0.f);
        ((float*)outp)[(size_t)node * 64 + lane] = acc;
    }
}

// ---------------------------------------------------------------------------

extern "C" void kernel_launch(void* const* d_in, const int* in_sizes, int n_in,
                              void* d_out, int out_size, void* d_ws, size_t ws_size,
                              hipStream_t stream) {
    const float* x   = (const float*)d_in[0];
    const int*   ei  = (const int*)d_in[1];
    const float* nrm = (const float*)d_in[2];
    const float* W1  = (const float*)d_in[3];
    const float* b1  = (const float*)d_in[4];
    const float* W2  = (const float*)d_in[5];
    const float* b2  = (const float*)d_in[6];
    float* out = (float*)d_out;

    const int HID  = in_sizes[4];            // 128
    const int FEAT = in_sizes[3] / HID;      // 256
    const int EMB  = in_sizes[5] / HID;      // 64
    const int Nn   = in_sizes[0] / FEAT;     // 50000  (< 65536: packed fmt ok)
    const int E    = in_sizes[2];            // 550000
    const int Epad = E + 4 * Nn + 64;        // CSR with per-node x4 padding

    char* p = (char*)d_ws;
    auto alloc = [&](size_t bytes) {
        char* r = p;
        p += (bytes + 255) & ~(size_t)255;
        return r;
    };
    unsigned short* h1b    = (unsigned short*)alloc((size_t)Nn * HID * 2);
    unsigned short* a1b    = (unsigned short*)alloc((size_t)Nn * HID * 2);
    unsigned short* h2b    = (unsigned short*)alloc((size_t)Nn * EMB * 2);
    unsigned short* W1t    = (unsigned short*)alloc((size_t)HID * FEAT * 2);
    unsigned short* W2t    = (unsigned short*)alloc((size_t)EMB * HID * 2);
    int*            counts = (int*)           alloc((size_t)Nn * 4);
    int*            offs   = (int*)           alloc((size_t)(Nn + 1) * 4);
    int*            cursor = (int*)           alloc((size_t)Nn * 4);
    unsigned*       ent    = (unsigned*)      alloc((size_t)Epad * 4);
    int*            flag   = (int*)           alloc(256);
    int*            partial= (int*)           alloc(1024 * 4);
    int*            baseOf = (int*)           alloc(1024 * 4);

    // ---- CSR build (by destination, padded x4, packed entries) ----
    constexpr int SCAN_ITEMS = 8;
    const int scanBlocks = (Nn + 256 * SCAN_ITEMS - 1) / (256 * SCAN_ITEMS);

    hipMemsetAsync(counts, 0, (size_t)Nn * 4, stream);
    k_detect<<<1, 64, 0, stream>>>(ei, 2 * E, flag);
    k_wprep<<<64, 256, 0, stream>>>(W1, W2, W1t, W2t, FEAT, HID, EMB);
    k_count<<<(E + 255) / 256, 256, 0, stream>>>(ei, E, Nn, flag, counts);
    k_scan_partial<SCAN_ITEMS><<<scanBlocks, 256, 0, stream>>>(counts, partial, Nn);
    k_scan_base<<<1, 64, 0, stream>>>(partial, baseOf, offs, Nn, scanBlocks);
    k_scan_final<SCAN_ITEMS><<<scanBlocks, 256, 0, stream>>>(counts, baseOf, offs,
                                                             cursor, ent, Nn);
    k_scatter<<<(E + 255) / 256, 256, 0, stream>>>(ei, nrm, E, Nn, flag, cursor, ent);

    const int gemmBlocks = (Nn + 63) / 64;

    // ---- layer 1 ----
    k_gemm_mfma<64, 128, 2, 4, true, true><<<gemmBlocks, 256, 0, stream>>>(
        (const void*)x, W1t, (void*)h1b, Nn, FEAT, HID);
    k_agg<128, true, true><<<(Nn + 3) / 4, 256, 0, stream>>>(
        h1b, offs, ent, b1, (void*)a1b, Nn);

    // ---- layer 2 ----
    k_gemm_mfma<64, 64, 2, 2, false, true><<<gemmBlocks, 256, 0, stream>>>(
        (const void*)a1b, W2t, (void*)h2b, Nn, HID, EMB);
    k_agg<64, false, false><<<(Nn + 3) / 4, 256, 0, stream>>>(
        h2b, offs, ent, b2, (void*)out, Nn);
}

// Round 6
// 136.854 us; speedup vs baseline: 2.7959x; 1.0364x over previous
//
#include <hip/hip_runtime.h>
#include <stdint.h>

// ---------------------------------------------------------------------------
// PPMI-GNN forward: 2-layer GCN with bf16-MFMA GEMMs and bf16 gathers.
//   h1b = bf16(x @ W1); a1b = bf16(relu(agg(h1b) + b1))
//   h2b = bf16(a1b @ W2); out = agg(h2b) + b2
// CSR (by destination) built on device each call; entries packed u32 =
// (row<<16)|fp16(norm); per-node ranges padded to x4 -> branch-free gather.
// Round 6: replace in-graph hipMemsetAsync(counts) (rocclr fill kernel was
// ~40us for 200KB!) with fused k_init (zero counts + edge-layout detect).
// ---------------------------------------------------------------------------

typedef __attribute__((ext_vector_type(8))) short short8;   // 8 bf16
typedef __attribute__((ext_vector_type(4))) float f32x4;

__device__ __forceinline__ unsigned short f2bf(float f) {   // RNE f32->bf16
    unsigned u = __float_as_uint(f);
    return (unsigned short)((u + 0x7FFFu + ((u >> 16) & 1u)) >> 16);
}
__device__ __forceinline__ float bf_lo(unsigned v) { return __uint_as_float(v << 16); }
__device__ __forceinline__ float bf_hi(unsigned v) { return __uint_as_float(v & 0xFFFF0000u); }
__device__ __forceinline__ float bf1(unsigned short v) { return __uint_as_float((unsigned)v << 16); }
__device__ __forceinline__ unsigned short f2h(float f) {
    _Float16 h = (_Float16)f;
    return __builtin_bit_cast(unsigned short, h);
}
__device__ __forceinline__ float h2f(unsigned u16) {
    _Float16 h = __builtin_bit_cast(_Float16, (unsigned short)(u16 & 0xFFFFu));
    return (float)h;
}

// ---- init: zero counts (big grid, int4) + edge-layout detect in block 0 ---
__global__ __launch_bounds__(256) void k_init(int* __restrict__ counts, int n,
                                              const int* __restrict__ ei, int twoE,
                                              int* __restrict__ flag) {
    const int gid = blockIdx.x * blockDim.x + threadIdx.x;
    const int stride = gridDim.x * blockDim.x;
    int4* c4 = (int4*)counts;
    const int n4 = n >> 2;
    for (int j = gid; j < n4; j += stride) c4[j] = make_int4(0, 0, 0, 0);
    for (int j = (n4 << 2) + gid; j < n; j += stride) counts[j] = 0;
    if (blockIdx.x == 0 && threadIdx.x < 64) {   // wave 0: int32 vs int64 detect
        const int i = 1 + 2 * threadIdx.x;
        int z = (i < twoE) ? (ei[i] == 0) : 1;
        unsigned long long m = __ballot(z);
        if (threadIdx.x == 0) *flag = (m == ~0ULL) ? 1 : 0;
    }
}

__device__ __forceinline__ void load_edge(const int* __restrict__ ei, int E, int e,
                                          int is64, int& r, int& c) {
    if (is64) { r = ei[2 * e]; c = ei[2 * (E + e)]; }
    else      { r = ei[e];     c = ei[E + e]; }
}

__global__ void k_count(const int* __restrict__ ei, int E, int N,
                        const int* __restrict__ flag, int* __restrict__ counts) {
    int e = blockIdx.x * blockDim.x + threadIdx.x;
    if (e >= E) return;
    int is64 = *flag;
    int r, c; load_edge(ei, E, e, is64, r, c);
    if ((unsigned)c < (unsigned)N && (unsigned)r < (unsigned)N)
        atomicAdd(&counts[c], 1);
}

// ---------------- 3-phase multi-block exclusive scan (PADDED to 4) --------
template <int ITEMS>
__global__ __launch_bounds__(256) void k_scan_partial(const int* __restrict__ counts,
                                                      int* __restrict__ partial, int n) {
    const int tid = threadIdx.x;
    const int base = blockIdx.x * 256 * ITEMS + tid * ITEMS;
    int s = 0;
    #pragma unroll
    for (int i = 0; i < ITEMS; ++i) {
        int idx = base + i;
        if (idx < n) s += (counts[idx] + 3) & ~3;     // padded count
    }
    #pragma unroll
    for (int d = 32; d; d >>= 1) s += __shfl_down(s, d, 64);
    __shared__ int ws[4];
    if ((tid & 63) == 0) ws[tid >> 6] = s;
    __syncthreads();
    if (tid == 0) partial[blockIdx.x] = ws[0] + ws[1] + ws[2] + ws[3];
}

__global__ void k_scan_base(const int* __restrict__ partial, int* __restrict__ baseOf,
                            int* __restrict__ offs, int n, int nblocks) {
    const int lane = threadIdx.x;            // 64 threads
    int running = 0;
    for (int b0 = 0; b0 < nblocks; b0 += 64) {
        int idx = b0 + lane;
        int v = (idx < nblocks) ? partial[idx] : 0;
        int inc = v;
        #pragma unroll
        for (int d = 1; d < 64; d <<= 1) {
            int x = __shfl_up(inc, d, 64);
            if (lane >= d) inc += x;
        }
        if (idx < nblocks) baseOf[idx] = running + (inc - v);
        running += __shfl(inc, 63, 64);
    }
    if (lane == 0) offs[n] = running;
}

// Phase C: rescan with base; writes offs+cursor, zero-fills pad entries.
template <int ITEMS>
__global__ __launch_bounds__(256) void k_scan_final(const int* __restrict__ counts,
                                                    const int* __restrict__ baseOf,
                                                    int* __restrict__ offs,
                                                    int* __restrict__ cursor,
                                                    unsigned* __restrict__ ent, int n) {
    __shared__ int tsum[256];
    const int tid = threadIdx.x;
    const int base0 = blockIdx.x * 256 * ITEMS + tid * ITEMS;
    int v[ITEMS];
    int s = 0;
    #pragma unroll
    for (int i = 0; i < ITEMS; ++i) {
        int idx = base0 + i;
        v[i] = (idx < n) ? counts[idx] : 0;
        s += (v[i] + 3) & ~3;
    }
    tsum[tid] = s;
    __syncthreads();
    for (int d = 1; d < 256; d <<= 1) {
        int x = (tid >= d) ? tsum[tid - d] : 0;
        __syncthreads();
        tsum[tid] += x;
        __syncthreads();
    }
    int base = baseOf[blockIdx.x] + ((tid == 0) ? 0 : tsum[tid - 1]);
    #pragma unroll
    for (int i = 0; i < ITEMS; ++i) {
        int idx = base0 + i;
        if (idx < n) {
            offs[idx] = base; cursor[idx] = base;
            int pad = (v[i] + 3) & ~3;
            for (int j = v[i]; j < pad; ++j)       // <=3 pad slots
                ent[base + j] = 0u;                // row 0, w = +0.0h
            base += pad;
        }
    }
}

__global__ void k_scatter(const int* __restrict__ ei, const float* __restrict__ nrm,
                          int E, int N, const int* __restrict__ flag,
                          int* __restrict__ cursor, unsigned* __restrict__ ent) {
    int e = blockIdx.x * blockDim.x + threadIdx.x;
    if (e >= E) return;
    int is64 = *flag;
    int r, c; load_edge(ei, E, e, is64, r, c);
    if ((unsigned)c < (unsigned)N && (unsigned)r < (unsigned)N) {
        int p = atomicAdd(&cursor[c], 1);
        ent[p] = ((unsigned)r << 16) | (unsigned)f2h(nrm[e]);
    }
}

// ---------------- weight prep: W[K][N] f32 -> Wt[N][K] bf16 ----------------
__global__ void k_wprep(const float* __restrict__ W1, const float* __restrict__ W2,
                        unsigned short* __restrict__ W1t, unsigned short* __restrict__ W2t,
                        int FEAT, int HID, int EMB) {
    const int t1 = FEAT * HID, t2 = HID * EMB;
    for (int i = blockIdx.x * blockDim.x + threadIdx.x; i < t1 + t2;
         i += gridDim.x * blockDim.x) {
        if (i < t1) {
            int k = i / HID, n = i % HID;
            W1t[(size_t)n * FEAT + k] = f2bf(W1[i]);
        } else {
            int j = i - t1;
            int k = j / EMB, n = j % EMB;
            W2t[(size_t)n * HID + k] = f2bf(W2[j]);
        }
    }
}

// ---------------------------------------------------------------------------
// MFMA GEMM: C[M,N] = A[M,K] @ Bt[N,K]^T, bf16 operands, f32 acc, BK=64.
// BM=64, 4 waves (2x2). LDS rows 128B, XOR-swizzled both sides (T2).
// ---------------------------------------------------------------------------
template <int BM, int BN, int FM, int FN, bool A_F32, bool OUT_BF16>
__global__ __launch_bounds__(256) void k_gemm_mfma(const void* __restrict__ Ag,
                                                   const unsigned short* __restrict__ Bt,
                                                   void* __restrict__ Cv,
                                                   int M, int K, int N) {
    __shared__ char ldsA[BM * 128];
    __shared__ char ldsB[BN * 128];
    const int tid  = threadIdx.x;
    const int lane = tid & 63;
    const int wid  = tid >> 6;
    const int wr   = wid >> 1;
    const int wc   = wid & 1;
    const int m0   = blockIdx.x * BM;

    f32x4 acc[FM][FN] = {};

    for (int k0 = 0; k0 < K; k0 += 64) {
        // ---- stage A: BM x 64 -> bf16 LDS ----
        {
            const int row  = tid >> 2;        // BM==64
            const int kq   = tid & 3;         // 16 elems each
            const int grow = min(m0 + row, M - 1);
            const int kbb  = kq * 32;
            const int sw   = (row & 7) << 4;
            if (A_F32) {
                const float* src = (const float*)Ag + (size_t)grow * K + k0 + kq * 16;
                float4 v0 = ((const float4*)src)[0];
                float4 v1 = ((const float4*)src)[1];
                float4 v2 = ((const float4*)src)[2];
                float4 v3 = ((const float4*)src)[3];
                union { short8 s; unsigned short h[8]; } p0, p1;
                p0.h[0] = f2bf(v0.x); p0.h[1] = f2bf(v0.y);
                p0.h[2] = f2bf(v0.z); p0.h[3] = f2bf(v0.w);
                p0.h[4] = f2bf(v1.x); p0.h[5] = f2bf(v1.y);
                p0.h[6] = f2bf(v1.z); p0.h[7] = f2bf(v1.w);
                p1.h[0] = f2bf(v2.x); p1.h[1] = f2bf(v2.y);
                p1.h[2] = f2bf(v2.z); p1.h[3] = f2bf(v2.w);
                p1.h[4] = f2bf(v3.x); p1.h[5] = f2bf(v3.y);
                p1.h[6] = f2bf(v3.z); p1.h[7] = f2bf(v3.w);
                *(short8*)(ldsA + row * 128 + ( kbb       ^ sw)) = p0.s;
                *(short8*)(ldsA + row * 128 + ((kbb + 16) ^ sw)) = p1.s;
            } else {
                const unsigned short* src =
                    (const unsigned short*)Ag + (size_t)grow * K + k0 + kq * 16;
                short8 s0 = ((const short8*)src)[0];
                short8 s1 = ((const short8*)src)[1];
                *(short8*)(ldsA + row * 128 + ( kbb       ^ sw)) = s0;
                *(short8*)(ldsA + row * 128 + ((kbb + 16) ^ sw)) = s1;
            }
        }
        // ---- stage B: BN x 64 -> bf16 LDS ----
        if (BN == 128 || tid < 128) {
            const int row = tid >> 1;
            const int kh  = tid & 1;
            const int sw  = (row & 7) << 4;
            const short8* src = (const short8*)(Bt + (size_t)row * K + k0 + kh * 32);
            #pragma unroll
            for (int j = 0; j < 4; ++j) {
                short8 s = src[j];
                int kb = kh * 64 + j * 16;
                *(short8*)(ldsB + row * 128 + (kb ^ sw)) = s;
            }
        }
        __syncthreads();

        #pragma unroll
        for (int s = 0; s < 2; ++s) {
            const int klo = s * 64 + (lane >> 4) * 16;
            short8 af[FM], bfv[FN];
            #pragma unroll
            for (int i = 0; i < FM; ++i) {
                int r = wr * (FM * 16) + i * 16 + (lane & 15);
                af[i] = *(const short8*)(ldsA + r * 128 + (klo ^ ((r & 7) << 4)));
            }
            #pragma unroll
            for (int j = 0; j < FN; ++j) {
                int n = wc * (FN * 16) + j * 16 + (lane & 15);
                bfv[j] = *(const short8*)(ldsB + n * 128 + (klo ^ ((n & 7) << 4)));
            }
            #pragma unroll
            for (int i = 0; i < FM; ++i)
                #pragma unroll
                for (int j = 0; j < FN; ++j)
                    acc[i][j] = __builtin_amdgcn_mfma_f32_16x16x32_bf16(
                        af[i], bfv[j], acc[i][j], 0, 0, 0);
        }
        __syncthreads();
    }

    // epilogue: C/D layout col=lane&15, row=(lane>>4)*4+reg
    #pragma unroll
    for (int i = 0; i < FM; ++i) {
        const int rbase = m0 + wr * (FM * 16) + i * 16 + ((lane >> 4) << 2);
        #pragma unroll
        for (int j = 0; j < FN; ++j) {
            const int c = wc * (FN * 16) + j * 16 + (lane & 15);
            #pragma unroll
            for (int r = 0; r < 4; ++r)
                if (rbase + r < M) {
                    if (OUT_BF16)
                        ((unsigned short*)Cv)[(size_t)(rbase + r) * N + c] = f2bf(acc[i][j][r]);
                    else
                        ((float*)Cv)[(size_t)(rbase + r) * N + c] = acc[i][j][r];
                }
        }
    }
}

// ---------------------------------------------------------------------------
// Per-node gather-reduce over bf16 h, one wave per node, 4-edge unroll.
// Edge entries packed u32 = (row<<16)|fp16(w); ranges padded to x4 (entry 0).
// ---------------------------------------------------------------------------
template <int F, bool RELU, bool OUT_BF16>
__global__ __launch_bounds__(256) void k_agg(const unsigned short* __restrict__ h,
                                             const int* __restrict__ offs,
                                             const unsigned* __restrict__ ent,
                                             const float* __restrict__ bias,
                                             void* __restrict__ outp, int nnodes) {
    const int lane = threadIdx.x & 63;
    const int wid  = __builtin_amdgcn_readfirstlane(threadIdx.x >> 6);
    const int node = blockIdx.x * 4 + wid;
    if (node >= nnodes) return;
    const int beg = offs[node], end = offs[node + 1];   // (end-beg) % 4 == 0

    if (F == 128) {
        const unsigned* hp = (const unsigned*)h;        // 64 x (2 bf16) per row
        float2 a0 = {0.f, 0.f}, a1 = {0.f, 0.f}, a2 = {0.f, 0.f}, a3 = {0.f, 0.f};
        for (int e = beg; e < end; e += 4) {
            const unsigned e0 = ent[e+0], e1 = ent[e+1], e2 = ent[e+2], e3 = ent[e+3];
            const float w0 = h2f(e0), w1 = h2f(e1), w2 = h2f(e2), w3 = h2f(e3);
            const unsigned v0 = hp[(size_t)(e0 >> 16) * 64 + lane];
            const unsigned v1 = hp[(size_t)(e1 >> 16) * 64 + lane];
            const unsigned v2 = hp[(size_t)(e2 >> 16) * 64 + lane];
            const unsigned v3 = hp[(size_t)(e3 >> 16) * 64 + lane];
            a0.x = fmaf(w0, bf_lo(v0), a0.x); a0.y = fmaf(w0, bf_hi(v0), a0.y);
            a1.x = fmaf(w1, bf_lo(v1), a1.x); a1.y = fmaf(w1, bf_hi(v1), a1.y);
            a2.x = fmaf(w2, bf_lo(v2), a2.x); a2.y = fmaf(w2, bf_hi(v2), a2.y);
            a3.x = fmaf(w3, bf_lo(v3), a3.x); a3.y = fmaf(w3, bf_hi(v3), a3.y);
        }
        float2 acc;
        acc.x = (a0.x + a1.x) + (a2.x + a3.x);
        acc.y = (a0.y + a1.y) + (a2.y + a3.y);
        const float2 b = ((const float2*)bias)[lane];
        acc.x += b.x; acc.y += b.y;
        if (RELU) { acc.x = fmaxf(acc.x, 0.f); acc.y = fmaxf(acc.y, 0.f); }
        if (OUT_BF16) {
            unsigned pack = (unsigned)f2bf(acc.x) | ((unsigned)f2bf(acc.y) << 16);
            ((unsigned*)outp)[(size_t)node * 64 + lane] = pack;
        } else {
            ((float2*)outp)[(size_t)node * 64 + lane] = acc;
        }
    } else {  // F == 64: one ushort per lane
        float a0 = 0.f, a1 = 0.f, a2 = 0.f, a3 = 0.f;
        for (int e = beg; e < end; e += 4) {
            const unsigned e0 = ent[e+0], e1 = ent[e+1], e2 = ent[e+2], e3 = ent[e+3];
            const float w0 = h2f(e0), w1 = h2f(e1), w2 = h2f(e2), w3 = h2f(e3);
            const float f0 = bf1(h[(size_t)(e0 >> 16) * 64 + lane]);
            const float f1 = bf1(h[(size_t)(e1 >> 16) * 64 + lane]);
            const float f2 = bf1(h[(size_t)(e2 >> 16) * 64 + lane]);
            const float f3 = bf1(h[(size_t)(e3 >> 16) * 64 + lane]);
            a0 = fmaf(w0, f0, a0); a1 = fmaf(w1, f1, a1);
            a2 = fmaf(w2, f2, a2); a3 = fmaf(w3, f3, a3);
        }
        float acc = (a0 + a1) + (a2 + a3) + bias[lane];
        if (RELU) acc = fmaxf(acc, 0.f);
        ((float*)outp)[(size_t)node * 64 + lane] = acc;
    }
}

// ---------------------------------------------------------------------------

extern "C" void kernel_launch(void* const* d_in, const int* in_sizes, int n_in,
                              void* d_out, int out_size, void* d_ws, size_t ws_size,
                              hipStream_t stream) {
    const float* x   = (const float*)d_in[0];
    const int*   ei  = (const int*)d_in[1];
    const float* nrm = (const float*)d_in[2];
    const float* W1  = (const float*)d_in[3];
    const float* b1  = (const float*)d_in[4];
    const float* W2  = (const float*)d_in[5];
    const float* b2  = (const float*)d_in[6];
    float* out = (float*)d_out;

    const int HID  = in_sizes[4];            // 128
    const int FEAT = in_sizes[3] / HID;      // 256
    const int EMB  = in_sizes[5] / HID;      // 64
    const int Nn   = in_sizes[0] / FEAT;     // 50000  (< 65536: packed fmt ok)
    const int E    = in_sizes[2];            // 550000
    const int Epad = E + 4 * Nn + 64;        // CSR with per-node x4 padding

    char* p = (char*)d_ws;
    auto alloc = [&](size_t bytes) {
        char* r = p;
        p += (bytes + 255) & ~(size_t)255;
        return r;
    };
    unsigned short* h1b    = (unsigned short*)alloc((size_t)Nn * HID * 2);
    unsigned short* a1b    = (unsigned short*)alloc((size_t)Nn * HID * 2);
    unsigned short* h2b    = (unsigned short*)alloc((size_t)Nn * EMB * 2);
    unsigned short* W1t    = (unsigned short*)alloc((size_t)HID * FEAT * 2);
    unsigned short* W2t    = (unsigned short*)alloc((size_t)EMB * HID * 2);
    int*            counts = (int*)           alloc((size_t)Nn * 4);
    int*            offs   = (int*)           alloc((size_t)(Nn + 1) * 4);
    int*            cursor = (int*)           alloc((size_t)Nn * 4);
    unsigned*       ent    = (unsigned*)      alloc((size_t)Epad * 4);
    int*            flag   = (int*)           alloc(256);
    int*            partial= (int*)           alloc(1024 * 4);
    int*            baseOf = (int*)           alloc(1024 * 4);

    // ---- CSR build (by destination, padded x4, packed entries) ----
    constexpr int SCAN_ITEMS = 8;
    const int scanBlocks = (Nn + 256 * SCAN_ITEMS - 1) / (256 * SCAN_ITEMS);

    k_init<<<128, 256, 0, stream>>>(counts, Nn, ei, 2 * E, flag);
    k_wprep<<<64, 256, 0, stream>>>(W1, W2, W1t, W2t, FEAT, HID, EMB);
    k_count<<<(E + 255) / 256, 256, 0, stream>>>(ei, E, Nn, flag, counts);
    k_scan_partial<SCAN_ITEMS><<<scanBlocks, 256, 0, stream>>>(counts, partial, Nn);
    k_scan_base<<<1, 64, 0, stream>>>(partial, baseOf, offs, Nn, scanBlocks);
    k_scan_final<SCAN_ITEMS><<<scanBlocks, 256, 0, stream>>>(counts, baseOf, offs,
                                                             cursor, ent, Nn);
    k_scatter<<<(E + 255) / 256, 256, 0, stream>>>(ei, nrm, E, Nn, flag, cursor, ent);

    const int gemmBlocks = (Nn + 63) / 64;

    // ---- layer 1 ----
    k_gemm_mfma<64, 128, 2, 4, true, true><<<gemmBlocks, 256, 0, stream>>>(
        (const void*)x, W1t, (void*)h1b, Nn, FEAT, HID);
    k_agg<128, true, true><<<(Nn + 3) / 4, 256, 0, stream>>>(
        h1b, offs, ent, b1, (void*)a1b, Nn);

    // ---- layer 2 ----
    k_gemm_mfma<64, 64, 2, 2, false, true><<<gemmBlocks, 256, 0, stream>>>(
        (const void*)a1b, W2t, (void*)h2b, Nn, HID, EMB);
    k_agg<64, false, false><<<(Nn + 3) / 4, 256, 0, stream>>>(
        h2b, offs, ent, b2, (void*)out, Nn);
}

// Round 8
// 135.580 us; speedup vs baseline: 2.8221x; 1.0094x over previous
//
#include <hip/hip_runtime.h>
#include <stdint.h>

// ---------------------------------------------------------------------------
// PPMI-GNN forward: 2-layer GCN with bf16-MFMA GEMMs and bf16 gathers.
//   h1b = bf16(x @ W1); a1b = bf16(relu(agg(h1b) + b1))
//   h2b = bf16(a1b @ W2); out = agg(h2b) + b2
// CSR (by destination) rebuilt on device each call; entries packed u32 =
// (row<<16)|fp16(norm); per-node ranges padded to x4 -> branch-free gather.
// Round 8: fix r7 UB (cross-uint4 stack aliasing in k_count_pack) -> proper
// local array + two explicit uint4 stores. Structure otherwise as r7:
//   - k_init fuses counts-zero + layout-detect + weight transpose
//   - k_count_pack: 4 edges/thread vectorized; emits 8B records for scatter
//   - k_scan_final self-computes its base (no separate scan_base launch)
//   - k_scatter2 consumes packed records (4.4MB) instead of ei+nrm (11MB)
// ---------------------------------------------------------------------------

typedef __attribute__((ext_vector_type(8))) short short8;   // 8 bf16
typedef __attribute__((ext_vector_type(4))) float f32x4;

__device__ __forceinline__ unsigned short f2bf(float f) {   // RNE f32->bf16
    unsigned u = __float_as_uint(f);
    return (unsigned short)((u + 0x7FFFu + ((u >> 16) & 1u)) >> 16);
}
__device__ __forceinline__ float bf_lo(unsigned v) { return __uint_as_float(v << 16); }
__device__ __forceinline__ float bf_hi(unsigned v) { return __uint_as_float(v & 0xFFFF0000u); }
__device__ __forceinline__ float bf1(unsigned short v) { return __uint_as_float((unsigned)v << 16); }
__device__ __forceinline__ unsigned short f2h(float f) {
    _Float16 h = (_Float16)f;
    return __builtin_bit_cast(unsigned short, h);
}
__device__ __forceinline__ float h2f(unsigned u16) {
    _Float16 h = __builtin_bit_cast(_Float16, (unsigned short)(u16 & 0xFFFFu));
    return (float)h;
}

// ---- init: zero counts + edge-layout detect + weight transpose (fused) ----
__global__ __launch_bounds__(256) void k_init(int* __restrict__ counts, int n,
                                              const int* __restrict__ ei, int twoE,
                                              int* __restrict__ flag,
                                              const float* __restrict__ W1,
                                              const float* __restrict__ W2,
                                              unsigned short* __restrict__ W1t,
                                              unsigned short* __restrict__ W2t,
                                              int FEAT, int HID, int EMB) {
    const int gid = blockIdx.x * blockDim.x + threadIdx.x;
    const int stride = gridDim.x * blockDim.x;
    // zero counts (int4)
    int4* c4 = (int4*)counts;
    const int n4 = n >> 2;
    for (int j = gid; j < n4; j += stride) c4[j] = make_int4(0, 0, 0, 0);
    for (int j = (n4 << 2) + gid; j < n; j += stride) counts[j] = 0;
    // weight transpose W[K][N] -> Wt[N][K] bf16
    const int t1 = FEAT * HID, t2 = HID * EMB;
    for (int i = gid; i < t1 + t2; i += stride) {
        if (i < t1) {
            int k = i / HID, nn = i % HID;
            W1t[(size_t)nn * FEAT + k] = f2bf(W1[i]);
        } else {
            int j = i - t1;
            int k = j / EMB, nn = j % EMB;
            W2t[(size_t)nn * HID + k] = f2bf(W2[j]);
        }
    }
    // int32 vs int64 detect (wave 0 of block 0)
    if (blockIdx.x == 0 && threadIdx.x < 64) {
        const int i = 1 + 2 * threadIdx.x;
        int z = (i < twoE) ? (ei[i] == 0) : 1;
        unsigned long long m = __ballot(z);
        if (threadIdx.x == 0) *flag = (m == ~0ULL) ? 1 : 0;
    }
}

// ---- count + pack: 4 edges/thread; rec = {(r<<16)|c, fp16(norm)} 8B -------
// invalid edge encoded as a-word 0xFFFFFFFF (c=0xFFFF impossible: N<=65535).
__global__ __launch_bounds__(256) void k_count_pack(const int* __restrict__ ei,
                                                    const float* __restrict__ nrm,
                                                    int E, int N,
                                                    const int* __restrict__ flag,
                                                    int* __restrict__ counts,
                                                    unsigned* __restrict__ rec) {
    const int e0 = (blockIdx.x * blockDim.x + threadIdx.x) * 4;
    if (e0 >= E) return;
    const int is64 = *flag;

    int r[4], c[4];
    if (e0 + 3 < E) {
        if (is64) {
            const int4* pr = (const int4*)(ei + 2 * e0);
            const int4* pc = (const int4*)(ei + 2 * E + 2 * e0);
            int4 r01 = pr[0], r23 = pr[1], c01 = pc[0], c23 = pc[1];
            r[0] = r01.x; r[1] = r01.z; r[2] = r23.x; r[3] = r23.z;
            c[0] = c01.x; c[1] = c01.z; c[2] = c23.x; c[3] = c23.z;
        } else {
            int4 rr = *(const int4*)(ei + e0);
            int4 cc = *(const int4*)(ei + E + e0);
            r[0] = rr.x; r[1] = rr.y; r[2] = rr.z; r[3] = rr.w;
            c[0] = cc.x; c[1] = cc.y; c[2] = cc.z; c[3] = cc.w;
        }
        const float4 w4 = *(const float4*)(nrm + e0);
        const float wv[4] = {w4.x, w4.y, w4.z, w4.w};
        unsigned ow[8];                       // registers (fully unrolled)
        #pragma unroll
        for (int i = 0; i < 4; ++i) {
            unsigned a = 0xFFFFFFFFu, b = 0u;
            if ((unsigned)c[i] < (unsigned)N && (unsigned)r[i] < (unsigned)N) {
                a = ((unsigned)r[i] << 16) | (unsigned)c[i];
                b = (unsigned)f2h(wv[i]);
                atomicAdd(&counts[c[i]], 1);
            }
            ow[2 * i + 0] = a;
            ow[2 * i + 1] = b;
        }
        uint4* dst = (uint4*)(rec + 2 * (size_t)e0);
        dst[0] = make_uint4(ow[0], ow[1], ow[2], ow[3]);
        dst[1] = make_uint4(ow[4], ow[5], ow[6], ow[7]);
    } else {
        for (int i = 0; i < 4 && e0 + i < E; ++i) {
            int rr, cc;
            const int e = e0 + i;
            if (is64) { rr = ei[2 * e]; cc = ei[2 * (E + e)]; }
            else      { rr = ei[e];     cc = ei[E + e]; }
            unsigned a = 0xFFFFFFFFu, b = 0u;
            if ((unsigned)cc < (unsigned)N && (unsigned)rr < (unsigned)N) {
                a = ((unsigned)rr << 16) | (unsigned)cc;
                b = (unsigned)f2h(nrm[e]);
                atomicAdd(&counts[cc], 1);
            }
            rec[2 * (size_t)e + 0] = a;
            rec[2 * (size_t)e + 1] = b;
        }
    }
}

// ---------------- scan phase A: per-block padded sums ----------------------
template <int ITEMS>
__global__ __launch_bounds__(256) void k_scan_partial(const int* __restrict__ counts,
                                                      int* __restrict__ partial, int n) {
    const int tid = threadIdx.x;
    const int base = blockIdx.x * 256 * ITEMS + tid * ITEMS;
    int s = 0;
    #pragma unroll
    for (int i = 0; i < ITEMS; ++i) {
        int idx = base + i;
        if (idx < n) s += (counts[idx] + 3) & ~3;     // padded count
    }
    #pragma unroll
    for (int d = 32; d; d >>= 1) s += __shfl_down(s, d, 64);
    __shared__ int ws[4];
    if ((tid & 63) == 0) ws[tid >> 6] = s;
    __syncthreads();
    if (tid == 0) partial[blockIdx.x] = ws[0] + ws[1] + ws[2] + ws[3];
}

// ---------------- scan phase B+C fused: self-base rescan -------------------
// REQUIRES nblocks <= 64 (ITEMS=8 -> 25 blocks for n=50000).
template <int ITEMS>
__global__ __launch_bounds__(256) void k_scan_final(const int* __restrict__ counts,
                                                    const int* __restrict__ partial,
                                                    int nblocks,
                                                    int* __restrict__ offs,
                                                    int* __restrict__ cursor,
                                                    unsigned* __restrict__ ent, int n) {
    __shared__ int tsum[256];
    __shared__ int blkBase, grandTot;
    const int tid = threadIdx.x;
    // wave 0: scan the <=64 block partials to find this block's base + total
    if (tid < 64) {
        int v = (tid < nblocks) ? partial[tid] : 0;
        int inc = v;
        #pragma unroll
        for (int d = 1; d < 64; d <<= 1) {
            int x = __shfl_up(inc, d, 64);
            if (tid >= d) inc += x;
        }
        if (tid == (int)blockIdx.x) blkBase = inc - v;
        if (tid == 63) grandTot = inc;
    }
    const int base0 = blockIdx.x * 256 * ITEMS + tid * ITEMS;
    int v[ITEMS];
    int s = 0;
    #pragma unroll
    for (int i = 0; i < ITEMS; ++i) {
        int idx = base0 + i;
        v[i] = (idx < n) ? counts[idx] : 0;
        s += (v[i] + 3) & ~3;
    }
    tsum[tid] = s;
    __syncthreads();
    for (int d = 1; d < 256; d <<= 1) {
        int x = (tid >= d) ? tsum[tid - d] : 0;
        __syncthreads();
        tsum[tid] += x;
        __syncthreads();
    }
    if (blockIdx.x == 0 && tid == 0) offs[n] = grandTot;
    int base = blkBase + ((tid == 0) ? 0 : tsum[tid - 1]);
    #pragma unroll
    for (int i = 0; i < ITEMS; ++i) {
        int idx = base0 + i;
        if (idx < n) {
            offs[idx] = base; cursor[idx] = base;
            int pad = (v[i] + 3) & ~3;
            for (int j = v[i]; j < pad; ++j)       // <=3 pad slots
                ent[base + j] = 0u;                // row 0, w = +0.0h
            base += pad;
        }
    }
}

// ---- scatter from packed records: 4 recs/thread ---------------------------
__global__ __launch_bounds__(256) void k_scatter2(const unsigned* __restrict__ rec,
                                                  int E, int* __restrict__ cursor,
                                                  unsigned* __restrict__ ent) {
    const int e0 = (blockIdx.x * blockDim.x + threadIdx.x) * 4;
    if (e0 >= E) return;
    if (e0 + 3 < E) {
        const uint4* src = (const uint4*)(rec + 2 * (size_t)e0);
        uint4 w0 = src[0], w1 = src[1];
        unsigned a[4] = {w0.x, w0.z, w1.x, w1.z};
        unsigned b[4] = {w0.y, w0.w, w1.y, w1.w};
        #pragma unroll
        for (int i = 0; i < 4; ++i) {
            if (a[i] != 0xFFFFFFFFu) {
                int cdst = (int)(a[i] & 0xFFFFu);
                int p = atomicAdd(&cursor[cdst], 1);
                ent[p] = (a[i] & 0xFFFF0000u) | b[i];
            }
        }
    } else {
        for (int i = 0; i < 4 && e0 + i < E; ++i) {
            unsigned a = rec[2 * (size_t)(e0 + i)];
            unsigned b = rec[2 * (size_t)(e0 + i) + 1];
            if (a != 0xFFFFFFFFu) {
                int cdst = (int)(a & 0xFFFFu);
                int p = atomicAdd(&cursor[cdst], 1);
                ent[p] = (a & 0xFFFF0000u) | b;
            }
        }
    }
}

// ---------------------------------------------------------------------------
// MFMA GEMM: C[M,N] = A[M,K] @ Bt[N,K]^T, bf16 operands, f32 acc, BK=64.
// BM=64, 4 waves (2x2). LDS rows 128B, XOR-swizzled both sides (T2).
// ---------------------------------------------------------------------------
template <int BM, int BN, int FM, int FN, bool A_F32, bool OUT_BF16>
__global__ __launch_bounds__(256) void k_gemm_mfma(const void* __restrict__ Ag,
                                                   const unsigned short* __restrict__ Bt,
                                                   void* __restrict__ Cv,
                                                   int M, int K, int N) {
    __shared__ char ldsA[BM * 128];
    __shared__ char ldsB[BN * 128];
    const int tid  = threadIdx.x;
    const int lane = tid & 63;
    const int wid  = tid >> 6;
    const int wr   = wid >> 1;
    const int wc   = wid & 1;
    const int m0   = blockIdx.x * BM;

    f32x4 acc[FM][FN] = {};

    for (int k0 = 0; k0 < K; k0 += 64) {
        // ---- stage A: BM x 64 -> bf16 LDS ----
        {
            const int row  = tid >> 2;        // BM==64
            const int kq   = tid & 3;         // 16 elems each
            const int grow = min(m0 + row, M - 1);
            const int kbb  = kq * 32;
            const int sw   = (row & 7) << 4;
            if (A_F32) {
                const float* src = (const float*)Ag + (size_t)grow * K + k0 + kq * 16;
                float4 v0 = ((const float4*)src)[0];
                float4 v1 = ((const float4*)src)[1];
                float4 v2 = ((const float4*)src)[2];
                float4 v3 = ((const float4*)src)[3];
                union { short8 s; unsigned short h[8]; } p0, p1;
                p0.h[0] = f2bf(v0.x); p0.h[1] = f2bf(v0.y);
                p0.h[2] = f2bf(v0.z); p0.h[3] = f2bf(v0.w);
                p0.h[4] = f2bf(v1.x); p0.h[5] = f2bf(v1.y);
                p0.h[6] = f2bf(v1.z); p0.h[7] = f2bf(v1.w);
                p1.h[0] = f2bf(v2.x); p1.h[1] = f2bf(v2.y);
                p1.h[2] = f2bf(v2.z); p1.h[3] = f2bf(v2.w);
                p1.h[4] = f2bf(v3.x); p1.h[5] = f2bf(v3.y);
                p1.h[6] = f2bf(v3.z); p1.h[7] = f2bf(v3.w);
                *(short8*)(ldsA + row * 128 + ( kbb       ^ sw)) = p0.s;
                *(short8*)(ldsA + row * 128 + ((kbb + 16) ^ sw)) = p1.s;
            } else {
                const unsigned short* src =
                    (const unsigned short*)Ag + (size_t)grow * K + k0 + kq * 16;
                short8 s0 = ((const short8*)src)[0];
                short8 s1 = ((const short8*)src)[1];
                *(short8*)(ldsA + row * 128 + ( kbb       ^ sw)) = s0;
                *(short8*)(ldsA + row * 128 + ((kbb + 16) ^ sw)) = s1;
            }
        }
        // ---- stage B: BN x 64 -> bf16 LDS ----
        if (BN == 128 || tid < 128) {
            const int row = tid >> 1;
            const int kh  = tid & 1;
            const int sw  = (row & 7) << 4;
            const short8* src = (const short8*)(Bt + (size_t)row * K + k0 + kh * 32);
            #pragma unroll
            for (int j = 0; j < 4; ++j) {
                short8 s = src[j];
                int kb = kh * 64 + j * 16;
                *(short8*)(ldsB + row * 128 + (kb ^ sw)) = s;
            }
        }
        __syncthreads();

        #pragma unroll
        for (int s = 0; s < 2; ++s) {
            const int klo = s * 64 + (lane >> 4) * 16;
            short8 af[FM], bfv[FN];
            #pragma unroll
            for (int i = 0; i < FM; ++i) {
                int r = wr * (FM * 16) + i * 16 + (lane & 15);
                af[i] = *(const short8*)(ldsA + r * 128 + (klo ^ ((r & 7) << 4)));
            }
            #pragma unroll
            for (int j = 0; j < FN; ++j) {
                int n = wc * (FN * 16) + j * 16 + (lane & 15);
                bfv[j] = *(const short8*)(ldsB + n * 128 + (klo ^ ((n & 7) << 4)));
            }
            #pragma unroll
            for (int i = 0; i < FM; ++i)
                #pragma unroll
                for (int j = 0; j < FN; ++j)
                    acc[i][j] = __builtin_amdgcn_mfma_f32_16x16x32_bf16(
                        af[i], bfv[j], acc[i][j], 0, 0, 0);
        }
        __syncthreads();
    }

    // epilogue: C/D layout col=lane&15, row=(lane>>4)*4+reg
    #pragma unroll
    for (int i = 0; i < FM; ++i) {
        const int rbase = m0 + wr * (FM * 16) + i * 16 + ((lane >> 4) << 2);
        #pragma unroll
        for (int j = 0; j < FN; ++j) {
            const int c = wc * (FN * 16) + j * 16 + (lane & 15);
            #pragma unroll
            for (int r = 0; r < 4; ++r)
                if (rbase + r < M) {
                    if (OUT_BF16)
                        ((unsigned short*)Cv)[(size_t)(rbase + r) * N + c] = f2bf(acc[i][j][r]);
                    else
                        ((float*)Cv)[(size_t)(rbase + r) * N + c] = acc[i][j][r];
                }
        }
    }
}

// ---------------------------------------------------------------------------
// Per-node gather-reduce over bf16 h, one wave per node, 4-edge unroll.
// Edge entries packed u32 = (row<<16)|fp16(w); ranges padded to x4 (entry 0).
// ---------------------------------------------------------------------------
template <int F, bool RELU, bool OUT_BF16>
__global__ __launch_bounds__(256) void k_agg(const unsigned short* __restrict__ h,
                                             const int* __restrict__ offs,
                                             const unsigned* __restrict__ ent,
                                             const float* __restrict__ bias,
                                             void* __restrict__ outp, int nnodes) {
    const int lane = threadIdx.x & 63;
    const int wid  = __builtin_amdgcn_readfirstlane(threadIdx.x >> 6);
    const int node = blockIdx.x * 4 + wid;
    if (node >= nnodes) return;
    const int beg = offs[node], end = offs[node + 1];   // (end-beg) % 4 == 0

    if (F == 128) {
        const unsigned* hp = (const unsigned*)h;        // 64 x (2 bf16) per row
        float2 a0 = {0.f, 0.f}, a1 = {0.f, 0.f}, a2 = {0.f, 0.f}, a3 = {0.f, 0.f};
        for (int e = beg; e < end; e += 4) {
            const uint4 q = *(const uint4*)(ent + e);   // 16B aligned (beg%4==0)
            const float w0 = h2f(q.x), w1 = h2f(q.y), w2 = h2f(q.z), w3 = h2f(q.w);
            const unsigned v0 = hp[(size_t)(q.x >> 16) * 64 + lane];
            const unsigned v1 = hp[(size_t)(q.y >> 16) * 64 + lane];
            const unsigned v2 = hp[(size_t)(q.z >> 16) * 64 + lane];
            const unsigned v3 = hp[(size_t)(q.w >> 16) * 64 + lane];
            a0.x = fmaf(w0, bf_lo(v0), a0.x); a0.y = fmaf(w0, bf_hi(v0), a0.y);
            a1.x = fmaf(w1, bf_lo(v1), a1.x); a1.y = fmaf(w1, bf_hi(v1), a1.y);
            a2.x = fmaf(w2, bf_lo(v2), a2.x); a2.y = fmaf(w2, bf_hi(v2), a2.y);
            a3.x = fmaf(w3, bf_lo(v3), a3.x); a3.y = fmaf(w3, bf_hi(v3), a3.y);
        }
        float2 acc;
        acc.x = (a0.x + a1.x) + (a2.x + a3.x);
        acc.y = (a0.y + a1.y) + (a2.y + a3.y);
        const float2 b = ((const float2*)bias)[lane];
        acc.x += b.x; acc.y += b.y;
        if (RELU) { acc.x = fmaxf(acc.x, 0.f); acc.y = fmaxf(acc.y, 0.f); }
        if (OUT_BF16) {
            unsigned pack = (unsigned)f2bf(acc.x) | ((unsigned)f2bf(acc.y) << 16);
            ((unsigned*)outp)[(size_t)node * 64 + lane] = pack;
        } else {
            ((float2*)outp)[(size_t)node * 64 + lane] = acc;
        }
    } else {  // F == 64: one ushort per lane
        float a0 = 0.f, a1 = 0.f, a2 = 0.f, a3 = 0.f;
        for (int e = beg; e < end; e += 4) {
            const uint4 q = *(const uint4*)(ent + e);
            const float w0 = h2f(q.x), w1 = h2f(q.y), w2 = h2f(q.z), w3 = h2f(q.w);
            const float f0 = bf1(h[(size_t)(q.x >> 16) * 64 + lane]);
            const float f1 = bf1(h[(size_t)(q.y >> 16) * 64 + lane]);
            const float f2 = bf1(h[(size_t)(q.z >> 16) * 64 + lane]);
            const float f3 = bf1(h[(size_t)(q.w >> 16) * 64 + lane]);
            a0 = fmaf(w0, f0, a0); a1 = fmaf(w1, f1, a1);
            a2 = fmaf(w2, f2, a2); a3 = fmaf(w3, f3, a3);
        }
        float acc = (a0 + a1) + (a2 + a3) + bias[lane];
        if (RELU) acc = fmaxf(acc, 0.f);
        ((float*)outp)[(size_t)node * 64 + lane] = acc;
    }
}

// ---------------------------------------------------------------------------

extern "C" void kernel_launch(void* const* d_in, const int* in_sizes, int n_in,
                              void* d_out, int out_size, void* d_ws, size_t ws_size,
                              hipStream_t stream) {
    const float* x   = (const float*)d_in[0];
    const int*   ei  = (const int*)d_in[1];
    const float* nrm = (const float*)d_in[2];
    const float* W1  = (const float*)d_in[3];
    const float* b1  = (const float*)d_in[4];
    const float* W2  = (const float*)d_in[5];
    const float* b2  = (const float*)d_in[6];
    float* out = (float*)d_out;

    const int HID  = in_sizes[4];            // 128
    const int FEAT = in_sizes[3] / HID;      // 256
    const int EMB  = in_sizes[5] / HID;      // 64
    const int Nn   = in_sizes[0] / FEAT;     // 50000  (< 65536: packed fmt ok)
    const int E    = in_sizes[2];            // 550000
    const int Epad = E + 4 * Nn + 64;        // CSR with per-node x4 padding

    char* p = (char*)d_ws;
    auto alloc = [&](size_t bytes) {
        char* r = p;
        p += (bytes + 255) & ~(size_t)255;
        return r;
    };
    unsigned short* h1b    = (unsigned short*)alloc((size_t)Nn * HID * 2);
    unsigned short* a1b    = (unsigned short*)alloc((size_t)Nn * HID * 2);
    unsigned short* h2b    = (unsigned short*)alloc((size_t)Nn * EMB * 2);
    unsigned short* W1t    = (unsigned short*)alloc((size_t)HID * FEAT * 2);
    unsigned short* W2t    = (unsigned short*)alloc((size_t)EMB * HID * 2);
    int*            counts = (int*)           alloc((size_t)Nn * 4);
    int*            offs   = (int*)           alloc((size_t)(Nn + 1) * 4);
    int*            cursor = (int*)           alloc((size_t)Nn * 4);
    unsigned*       ent    = (unsigned*)      alloc((size_t)Epad * 4);
    unsigned*       rec    = (unsigned*)      alloc((size_t)E * 8);
    int*            flag   = (int*)           alloc(256);
    int*            partial= (int*)           alloc(1024 * 4);

    // ---- CSR build (by destination, padded x4, packed entries) ----
    constexpr int SCAN_ITEMS = 8;             // 2048/block -> 25 blocks (<=64!)
    const int scanBlocks = (Nn + 256 * SCAN_ITEMS - 1) / (256 * SCAN_ITEMS);
    const int edgeBlocks4 = (E / 4 + 255) / 256 + 1;

    k_init<<<128, 256, 0, stream>>>(counts, Nn, ei, 2 * E, flag,
                                    W1, W2, W1t, W2t, FEAT, HID, EMB);
    k_count_pack<<<edgeBlocks4, 256, 0, stream>>>(ei, nrm, E, Nn, flag, counts, rec);
    k_scan_partial<SCAN_ITEMS><<<scanBlocks, 256, 0, stream>>>(counts, partial, Nn);
    k_scan_final<SCAN_ITEMS><<<scanBlocks, 256, 0, stream>>>(counts, partial, scanBlocks,
                                                             offs, cursor, ent, Nn);
    k_scatter2<<<edgeBlocks4, 256, 0, stream>>>(rec, E, cursor, ent);

    const int gemmBlocks = (Nn + 63) / 64;

    // ---- layer 1 ----
    k_gemm_mfma<64, 128, 2, 4, true, true><<<gemmBlocks, 256, 0, stream>>>(
        (const void*)x, W1t, (void*)h1b, Nn, FEAT, HID);
    k_agg<128, true, true><<<(Nn + 3) / 4, 256, 0, stream>>>(
        h1b, offs, ent, b1, (void*)a1b, Nn);

    // ---- layer 2 ----
    k_gemm_mfma<64, 64, 2, 2, false, true><<<gemmBlocks, 256, 0, stream>>>(
        (const void*)a1b, W2t, (void*)h2b, Nn, HID, EMB);
    k_agg<64, false, false><<<(Nn + 3) / 4, 256, 0, stream>>>(
        h2b, offs, ent, b2, (void*)out, Nn);
}